// Round 6
// baseline (337.473 us; speedup 1.0000x reference)
//
#include <hip/hip_runtime.h>

#define B_  4
#define D_  512
#define H_  8
#define DV_ 64
#define S_  2048
#define LOG2E 1.442695041f

typedef __bf16 bf16;
typedef bf16  bf16x8 __attribute__((ext_vector_type(8)));
typedef bf16  bf16x4 __attribute__((ext_vector_type(4)));
typedef float f32x4  __attribute__((ext_vector_type(4)));

#define MFMA(a, b, c) __builtin_amdgcn_mfma_f32_16x16x32_bf16((a), (b), (c), 0, 0, 0)

// async global->LDS, 16B per lane; LDS dest is wave-uniform base + lane*16
#define GLOAD_LDS(g, l)                                                     \
    __builtin_amdgcn_global_load_lds(                                       \
        (const __attribute__((address_space(1))) void*)(g),                 \
        (__attribute__((address_space(3))) void*)(l), 16, 0, 0)

// s_waitcnt with vmcnt(n), lgkm/exp unconstrained (gfx9 encoding)
#define WAIT_VMCNT(n)                                                       \
    __builtin_amdgcn_s_waitcnt(((n) & 15) | (((n) >> 4) << 14) | (7 << 4) | (15 << 8))

// ---------------------------------------------------------------------------
// Kernel 1: prep = transpose x (B,D,S fp32 -> B,S,D bf16)  +  pack weights
// ---------------------------------------------------------------------------
__global__ __launch_bounds__(256) void prep(
    const float* __restrict__ x, const float* __restrict__ Wq,
    const float* __restrict__ Wk, const float* __restrict__ Wv,
    const float* __restrict__ W0, bf16* __restrict__ xb, bf16* __restrict__ Wb) {
    const int bid = blockIdx.x;
    if (bid < 4096) {                            // transpose part
        __shared__ float tile[32][33];
        const int sblk = bid % 64;               // S/32
        const int dblk = (bid / 64) % 16;        // D/32
        const int b    = bid / 1024;
        const int d0 = dblk * 32, s0 = sblk * 32;
        const int tx = threadIdx.x & 31;
        const int ty = threadIdx.x >> 5;         // 0..7
        const float* xp = x + (size_t)b * D_ * S_;
#pragma unroll
        for (int i = 0; i < 32; i += 8)
            tile[ty + i][tx] = xp[(size_t)(d0 + ty + i) * S_ + s0 + tx];
        __syncthreads();
        bf16* xbp = xb + ((size_t)b * S_ + s0) * D_ + d0;
#pragma unroll
        for (int i = 0; i < 32; i += 8)
            xbp[(size_t)(ty + i) * D_ + tx] = (bf16)tile[tx][ty + i];
    } else {                                     // weight-pack part: 256 blocks
        const int f0 = ((bid - 4096) * 256 + threadIdx.x) * 16;  // 0..1048560
        const int src = f0 >> 18;                // 262144 elems per matrix
        const int off = f0 & 262143;
        const float* W = (src == 0) ? Wq : (src == 1) ? Wk : (src == 2) ? Wv : W0;
        float4 v0 = *(const float4*)&W[off];
        float4 v1 = *(const float4*)&W[off + 4];
        float4 v2 = *(const float4*)&W[off + 8];
        float4 v3 = *(const float4*)&W[off + 12];
        bf16x8 h0 = {(bf16)v0.x, (bf16)v0.y, (bf16)v0.z, (bf16)v0.w,
                     (bf16)v1.x, (bf16)v1.y, (bf16)v1.z, (bf16)v1.w};
        bf16x8 h1 = {(bf16)v2.x, (bf16)v2.y, (bf16)v2.z, (bf16)v2.w,
                     (bf16)v3.x, (bf16)v3.y, (bf16)v3.z, (bf16)v3.w};
        *(bf16x8*)&Wb[f0]     = h0;
        *(bf16x8*)&Wb[f0 + 8] = h1;
    }
}

// ---------------------------------------------------------------------------
// Kernel 2: fused QKV GEMM, m97-style core (r1-verified). V stored transposed
// + key-swizzled (sigma) for flash's LDS-staged PV fragments. T1 XCD swizzle.
// ---------------------------------------------------------------------------
__global__ __launch_bounds__(256) void gemm_qkv(
    const bf16* __restrict__ A, const bf16* __restrict__ Wb,
    const float* __restrict__ bq, const float* __restrict__ bk,
    const float* __restrict__ bv,
    bf16* __restrict__ Q, bf16* __restrict__ K, bf16* __restrict__ Vt) {
    __shared__ union {
        struct { bf16 A[8192]; bf16 B[8192]; } s;
        bf16 T[128][132];                        // epilogue transpose (33792 B)
    } sm;

    const int tid = threadIdx.x;
    const int w = tid >> 6, lane = tid & 63;
    const int m16 = lane & 15, quad = lane >> 4;
    const int wr = w & 1, wc = w >> 1;

    const int bid  = (blockIdx.x & 7) * 96 + (blockIdx.x >> 3);  // T1 swizzle
    const int nblk = bid % 12;                   // N = 1536 / 128
    const int mblk = bid / 12;                   // M = 8192 / 128
    const int m0 = mblk * 128, n0 = nblk * 128;

    f32x4 acc[4][4];
#pragma unroll
    for (int i = 0; i < 4; ++i)
#pragma unroll
        for (int j = 0; j < 4; ++j) acc[i][j] = (f32x4){0.f, 0.f, 0.f, 0.f};

    for (int k0 = 0; k0 < D_; k0 += 64) {
        __syncthreads();
#pragma unroll
        for (int i = 0; i < 4; ++i) {            // wave w stages chunks w*4..w*4+3
            const int c  = w * 4 + i;
            const int mt = c >> 1, kk = c & 1;
            const int row = mt * 16 + m16;
            const int col = k0 + kk * 32 + quad * 8;
            GLOAD_LDS(&A[(size_t)(m0 + row) * D_ + col],  &sm.s.A[(c * 64 + lane) * 8]);
            GLOAD_LDS(&Wb[(size_t)(n0 + row) * D_ + col], &sm.s.B[(c * 64 + lane) * 8]);
        }
        __syncthreads();
#pragma unroll
        for (int kk = 0; kk < 2; ++kk) {
            bf16x8 af[4], bfv[4];
#pragma unroll
            for (int t = 0; t < 4; ++t) {
                af[t]  = *(const bf16x8*)&sm.s.A[(((wr * 4 + t) * 2 + kk) * 64 + lane) * 8];
                bfv[t] = *(const bf16x8*)&sm.s.B[(((wc * 4 + t) * 2 + kk) * 64 + lane) * 8];
            }
#pragma unroll
            for (int mt = 0; mt < 4; ++mt)
#pragma unroll
                for (int nt = 0; nt < 4; ++nt)
                    acc[mt][nt] = MFMA(af[mt], bfv[nt], acc[mt][nt]);
        }
    }

    const int proj = n0 >> 9;                    // 128-tiles never straddle
    const float* bias = (proj == 0) ? bq : (proj == 1) ? bk : bv;

    if (proj == 2) {                             // V: direct sigma-swizzled store
#pragma unroll
        for (int mt = 0; mt < 4; ++mt)
#pragma unroll
            for (int nt = 0; nt < 4; ++nt) {
                const int nr = (n0 + wc * 64 + nt * 16 + m16) & 511;
                const int h = nr >> 6, e = nr & 63;
                const float bia = bias[nr];
                const int srow = m0 + wr * 64 + mt * 16 + quad * 4;
                const int b = srow >> 11, s = srow & 2047;
                const int s2 = (s & ~31) | (quad * 8 + (mt & 1) * 4);  // sigma
                bf16x4 hv;
#pragma unroll
                for (int r = 0; r < 4; ++r) hv[r] = (bf16)(acc[mt][nt][r] + bia);
                *(bf16x4*)&Vt[(((size_t)b * H_ + h) * DV_ + e) * S_ + s2] = hv;
            }
    } else {                                     // Q/K: LDS transpose -> bf16x8
        __syncthreads();
#pragma unroll
        for (int mt = 0; mt < 4; ++mt)
#pragma unroll
            for (int nt = 0; nt < 4; ++nt) {
                const int nloc = wc * 64 + nt * 16 + m16;
                const float bia = bias[(n0 + nloc) & 511];
#pragma unroll
                for (int r = 0; r < 4; ++r)
                    sm.T[wr * 64 + mt * 16 + quad * 4 + r][nloc] =
                        (bf16)(acc[mt][nt][r] + bia);
            }
        __syncthreads();
        const int rloc = tid >> 1, cb = (tid & 1) * 64;
        const int M = m0 + rloc, b = M >> 11, s = M & 2047;
        const int nrb = (n0 + cb) & 511;
        const int h = nrb >> 6;
        bf16* dst = ((proj == 0) ? Q : K) + (((size_t)b * H_ + h) * S_ + s) * DV_;
#pragma unroll
        for (int u = 0; u < 8; ++u)
            *(bf16x8*)&dst[u * 8] = *(const bf16x8*)&sm.T[rloc][cb + u * 8];
    }
}

// ---------------------------------------------------------------------------
// Kernel 3: flash attention v11 — r4 structure (verified 63.6us) with BM=128.
//  THEORY (r5 post-mortem): occupancy is NOT binding (q-split raised it and
//  regressed 2.2x via 4x LDS reads + 32 drain-barriers). At r4's 2 blocks/CU
//  VGPR has ~900/wave headroom -> spend registers: 128 q-rows per block
//  (qf[8][2], o[4][8], sc[2][8], pf[8]), grid 1024->512. Per-iter staging,
//  LDS reads, and vmcnt waits UNCHANGED; MFMA/iter 36->72, exp VALU 2x ->
//  the wait-stall gets filled with work. Conflict cycles halve (same/block,
//  half the blocks). All r4-verified algebra (sigma-V, XOR K-slot swizzle,
//  exp2 mask, split waits 12/8 + tail 4/0, zero barriers) verbatim.
// ---------------------------------------------------------------------------
__global__ __launch_bounds__(256, 2) void flash_attn(
    const bf16* __restrict__ Q, const bf16* __restrict__ K, const bf16* __restrict__ Vt,
    const float* __restrict__ mask, bf16* __restrict__ heads) {
    __shared__ union {
        struct {
            bf16 Kl[2][4][2048];                 // [buf][wave][32 keys x 64 d]
            bf16 Vl[2][4][2048];                 // [buf][wave][64 e x 32 keys]
            float Ms[2048];                      // mask * log2(e)
        } s;                                     // 73728 B
        struct { float O[64][130]; float L[128]; } red;   // 33792 B
    } sm;

    // XCD-aware swizzle: contiguous 64-block chunk per XCD (K/V L2 locality)
    const int bid  = blockIdx.x;                 // B*H*(S/128) = 512
    const int bidx = (bid & 7) * 64 + (bid >> 3);
    const int qblk = bidx & 15;                  // S/128 = 16
    const int h    = (bidx >> 4) & 7;
    const int b    = bidx >> 7;
    const int q0   = qblk * 128;

    const int tid = threadIdx.x;
    const int w = tid >> 6, lane = tid & 63;
    const int m16 = lane & 15, quad = lane >> 4;

    const bf16* Qp = Q  + ((size_t)b * H_ + h) * S_ * DV_;
    const bf16* Kp = K  + ((size_t)b * H_ + h) * S_ * DV_;
    const bf16* Vp = Vt + ((size_t)b * H_ + h) * DV_ * S_;
    const float* mp = mask + (size_t)b * S_;

    // per-lane staging constants (swizzle algebra, r1-verified)
    const int krow = lane >> 3;                          // 0..7
    const int kcol = ((lane & 7) ^ krow) * 8;            // elem offset in K row
    const int vrow = lane >> 2;                          // 0..15
    const int vcol = ((lane & 3) ^ (vrow & 3)) * 8;      // elem offset in V row

    // stage mask to LDS pre-scaled into the exp2 domain (retires pre-barrier)
#pragma unroll
    for (int p = 0; p < 2; ++p) {
        const float4 mv = *(const float4*)&mp[(p * 256 + tid) * 4];
        f32x4 t = {mv.x * LOG2E, mv.y * LOG2E, mv.z * LOG2E, mv.w * LOG2E};
        *(f32x4*)&sm.s.Ms[(p * 256 + tid) * 4] = t;
    }

    // Q B-frags for 128 q-rows, pre-scaled by 1/sqrt(64) (exact in bf16)
    bf16x8 qf[8][2];
#pragma unroll
    for (int qt = 0; qt < 8; ++qt)
#pragma unroll
        for (int kk = 0; kk < 2; ++kk) {
            bf16x8 v = *(const bf16x8*)&Qp[(size_t)(q0 + qt * 16 + m16) * DV_ +
                                           kk * 32 + quad * 8];
#pragma unroll
            for (int i = 0; i < 8; ++i) v[i] = (bf16)((float)v[i] * 0.125f);
            qf[qt][kk] = v;
        }

    bf16x8 ones;
#pragma unroll
    for (int i = 0; i < 8; ++i) ones[i] = (bf16)1.0f;

    f32x4 o[4][8];                               // O^T[e=16mt+4quad+r][q=16qt+m16]
    f32x4 lacc[8];
#pragma unroll
    for (int mt = 0; mt < 4; ++mt)
#pragma unroll
        for (int qt = 0; qt < 8; ++qt) o[mt][qt] = (f32x4){0.f, 0.f, 0.f, 0.f};
#pragma unroll
    for (int qt = 0; qt < 8; ++qt) lacc[qt] = (f32x4){0.f, 0.f, 0.f, 0.f};

    // ---- prologue: batch 0 (buf 0), K first then V; barrier drains vmcnt ----
    {
        const int tw = w * 32;
#pragma unroll
        for (int p = 0; p < 4; ++p)
            GLOAD_LDS(&Kp[(size_t)(tw + p * 8 + krow) * DV_ + kcol],
                      &sm.s.Kl[0][w][(p * 64 + lane) * 8]);
#pragma unroll
        for (int p = 0; p < 4; ++p)
            GLOAD_LDS(&Vp[(size_t)(p * 16 + vrow) * S_ + tw + vcol],
                      &sm.s.Vl[0][w][(p * 64 + lane) * 8]);
    }
    __syncthreads();                             // mask visible; batch0 done

    for (int i = 0; i < 16; ++i) {
        const int tw = i * 128 + w * 32;         // this wave's 32 keys
        if (i < 15) {                            // issue batch i+1 -> buf (i+1)&1
            const int twn = tw + 128;
            const int nb = (i + 1) & 1;
#pragma unroll
            for (int p = 0; p < 4; ++p)
                GLOAD_LDS(&Kp[(size_t)(twn + p * 8 + krow) * DV_ + kcol],
                          &sm.s.Kl[nb][w][(p * 64 + lane) * 8]);
#pragma unroll
            for (int p = 0; p < 4; ++p)
                GLOAD_LDS(&Vp[(size_t)(p * 16 + vrow) * S_ + twn + vcol],
                          &sm.s.Vl[nb][w][(p * 64 + lane) * 8]);
            WAIT_VMCNT(12);                      // K(i) in LDS (V(i) may lag)
        } else {
            WAIT_VMCNT(4);                       // K(15) in LDS
        }
        __builtin_amdgcn_sched_barrier(0);
        const int buf = i & 1;

        // K A-frags from LDS (swizzle-inverted: retrieves chunk kk*4+quad)
        bf16x8 kf[2][2];
#pragma unroll
        for (int tt = 0; tt < 2; ++tt)
#pragma unroll
            for (int kk = 0; kk < 2; ++kk)
                kf[tt][kk] = *(const bf16x8*)&sm.s.Kl[buf][w][
                    ((tt * 16 + m16) * 8 + ((kk * 4 + quad) ^ (m16 & 7))) * 8];
        const f32x4 m2a = *(const f32x4*)&sm.s.Ms[tw + quad * 4];
        const f32x4 m2b = *(const f32x4*)&sm.s.Ms[tw + 16 + quad * 4];

        // S^T tiles: sc[tt][qt], lane = p[t=16tt+4quad+r][q=16qt+m16]
        f32x4 sc[2][8];
#pragma unroll
        for (int tt = 0; tt < 2; ++tt)
#pragma unroll
            for (int qt = 0; qt < 8; ++qt) sc[tt][qt] = (f32x4){0.f, 0.f, 0.f, 0.f};
#pragma unroll
        for (int kk = 0; kk < 2; ++kk)
#pragma unroll
            for (int tt = 0; tt < 2; ++tt)
#pragma unroll
                for (int qt = 0; qt < 8; ++qt)
                    sc[tt][qt] = MFMA(kf[tt][kk], qf[qt][kk], sc[tt][qt]);

        // mask + exp2, directly into PV B-frags (in-lane, no LDS)
        f32x4 ngA, ngB;
#pragma unroll
        for (int r = 0; r < 4; ++r) {
            ngA[r] = (m2a[r] - LOG2E) * 8e29f;   // 0 for m=1, -1.15e30 for m=0
            ngB[r] = (m2b[r] - LOG2E) * 8e29f;
        }
        bf16x8 pf[8];
#pragma unroll
        for (int qt = 0; qt < 8; ++qt)
#pragma unroll
            for (int r = 0; r < 4; ++r) {
                pf[qt][r]     = (bf16)__builtin_amdgcn_exp2f(
                    __builtin_fmaf(sc[0][qt][r], m2a[r], ngA[r]));
                pf[qt][4 + r] = (bf16)__builtin_amdgcn_exp2f(
                    __builtin_fmaf(sc[1][qt][r], m2b[r], ngB[r]));
            }

        // l accumulation needs no V — overlap with V landing
#pragma unroll
        for (int qt = 0; qt < 8; ++qt) lacc[qt] = MFMA(ones, pf[qt], lacc[qt]);

        if (i < 15) WAIT_VMCNT(8);               // V(i) in LDS
        else        WAIT_VMCNT(0);
        __builtin_amdgcn_sched_barrier(0);

        // V A-frags from LDS (retrieves chunk quad)
        bf16x8 vf[4];
#pragma unroll
        for (int mt = 0; mt < 4; ++mt)
            vf[mt] = *(const bf16x8*)&sm.s.Vl[buf][w][
                ((mt * 16 + m16) * 4 + (quad ^ (m16 & 3))) * 8];

        // PV
#pragma unroll
        for (int mt = 0; mt < 4; ++mt)
#pragma unroll
            for (int qt = 0; qt < 8; ++qt) o[mt][qt] = MFMA(vf[mt], pf[qt], o[mt][qt]);
    }

    // ---- cross-wave reduction (turn-based accumulate into red) ----
    __syncthreads();
#pragma unroll
    for (int ww = 0; ww < 4; ++ww) {
        if (w == ww) {
#pragma unroll
            for (int mt = 0; mt < 4; ++mt)
#pragma unroll
                for (int qt = 0; qt < 8; ++qt)
#pragma unroll
                    for (int r = 0; r < 4; ++r) {
                        float* slot = &sm.red.O[mt * 16 + quad * 4 + r][qt * 16 + m16];
                        *slot = (ww == 0) ? o[mt][qt][r] : (*slot + o[mt][qt][r]);
                    }
            if (quad == 0)
#pragma unroll
                for (int qt = 0; qt < 8; ++qt) {
                    float* ls = &sm.red.L[qt * 16 + m16];
                    *ls = (ww == 0) ? lacc[qt][0] : (*ls + lacc[qt][0]);
                }
        }
        __syncthreads();
    }

    // ---- final store: thread -> (q = tid>>1, 32-wide e-chunk = (tid&1)*32) ----
    const int ql = tid >> 1, ec = (tid & 1) * 32;
    const float l  = sm.red.L[ql];
    const float qm = mp[q0 + ql];
    const float inv = qm / l;
    bf16x8 hv[4];
#pragma unroll
    for (int c = 0; c < 4; ++c)
#pragma unroll
        for (int i = 0; i < 8; ++i)
            hv[c][i] = (bf16)(sm.red.O[ec + c * 8 + i][ql] * inv);
    bf16* dst = &heads[((size_t)b * S_ + q0 + ql) * D_ + h * DV_ + ec];
    *(bf16x8*)(dst)      = hv[0];
    *(bf16x8*)(dst + 8)  = hv[1];
    *(bf16x8*)(dst + 16) = hv[2];
    *(bf16x8*)(dst + 24) = hv[3];
}

// ---------------------------------------------------------------------------
// Kernel 4: out projection (unchanged; T1 XCD swizzle)
// ---------------------------------------------------------------------------
__global__ __launch_bounds__(256) void gemm_out(
    const bf16* __restrict__ A, const bf16* __restrict__ Wb,
    const float* __restrict__ b0, float* __restrict__ outp) {
    __shared__ bf16 Asl[8192];
    __shared__ bf16 Bsl[8192];

    const int tid = threadIdx.x;
    const int w = tid >> 6, lane = tid & 63;
    const int m16 = lane & 15, quad = lane >> 4;
    const int wr = w & 1, wc = w >> 1;

    const int bid  = (blockIdx.x & 7) * 32 + (blockIdx.x >> 3);  // T1 swizzle
    const int nblk = bid & 3;                    // N = 512 / 128
    const int mblk = bid >> 2;                   // M = 8192 / 128
    const int m0 = mblk * 128, n0 = nblk * 128;

    f32x4 acc[4][4];
#pragma unroll
    for (int i = 0; i < 4; ++i)
#pragma unroll
        for (int j = 0; j < 4; ++j) acc[i][j] = (f32x4){0.f, 0.f, 0.f, 0.f};

    for (int k0 = 0; k0 < D_; k0 += 64) {
        __syncthreads();
#pragma unroll
        for (int i = 0; i < 4; ++i) {
            const int c  = w * 4 + i;
            const int mt = c >> 1, kk = c & 1;
            const int row = mt * 16 + m16;
            const int col = k0 + kk * 32 + quad * 8;
            GLOAD_LDS(&A[(size_t)(m0 + row) * D_ + col], &Asl[(c * 64 + lane) * 8]);
            GLOAD_LDS(&Wb[(size_t)(1536 + n0 + row) * D_ + col], &Bsl[(c * 64 + lane) * 8]);
        }
        __syncthreads();
#pragma unroll
        for (int kk = 0; kk < 2; ++kk) {
            bf16x8 af[4], bfv[4];
#pragma unroll
            for (int t = 0; t < 4; ++t) {
                af[t]  = *(const bf16x8*)&Asl[(((wr * 4 + t) * 2 + kk) * 64 + lane) * 8];
                bfv[t] = *(const bf16x8*)&Bsl[(((wc * 4 + t) * 2 + kk) * 64 + lane) * 8];
            }
#pragma unroll
            for (int mt = 0; mt < 4; ++mt)
#pragma unroll
                for (int nt = 0; nt < 4; ++nt)
                    acc[mt][nt] = MFMA(af[mt], bfv[nt], acc[mt][nt]);
        }
    }

#pragma unroll
    for (int mt = 0; mt < 4; ++mt)
#pragma unroll
        for (int nt = 0; nt < 4; ++nt) {
            const int n = n0 + wc * 64 + nt * 16 + m16;
            const float bia = b0[n];
            const int srow = m0 + wr * 64 + mt * 16 + quad * 4;
            const int b = srow >> 11, s = srow & 2047;
            float4 vv;
            vv.x = acc[mt][nt][0] + bia;
            vv.y = acc[mt][nt][1] + bia;
            vv.z = acc[mt][nt][2] + bia;
            vv.w = acc[mt][nt][3] + bia;
            *(float4*)&outp[((size_t)b * D_ + n) * S_ + s] = vv;
        }
}

// ---------------------------------------------------------------------------
extern "C" void kernel_launch(void* const* d_in, const int* in_sizes, int n_in,
                              void* d_out, int out_size, void* d_ws, size_t ws_size,
                              hipStream_t stream) {
    const float* x    = (const float*)d_in[0];
    const float* mask = (const float*)d_in[1];
    const float* Wq   = (const float*)d_in[2];
    const float* bq   = (const float*)d_in[3];
    const float* Wk   = (const float*)d_in[4];
    const float* bk   = (const float*)d_in[5];
    const float* Wv   = (const float*)d_in[6];
    const float* bv   = (const float*)d_in[7];
    const float* W0   = (const float*)d_in[8];
    const float* b0   = (const float*)d_in[9];
    float* out = (float*)d_out;

    char* ws = (char*)d_ws;
    const size_t SEG = (size_t)B_ * S_ * D_ * sizeof(bf16);   // 8 MiB
    bf16* xb    = (bf16*)(ws);            // reused as `heads` after gemm_qkv
    bf16* Qb    = (bf16*)(ws + SEG);
    bf16* Kb    = (bf16*)(ws + 2 * SEG);
    bf16* Vt    = (bf16*)(ws + 3 * SEG);
    bf16* Wb    = (bf16*)(ws + 4 * SEG);  // 2048x512 bf16 = 2 MiB
    bf16* heads = xb;

    prep<<<dim3(4096 + 256), dim3(256), 0, stream>>>(x, Wq, Wk, Wv, W0, xb, Wb);
    gemm_qkv<<<dim3(64 * 12), dim3(256), 0, stream>>>(xb, Wb, bq, bk, bv, Qb, Kb, Vt);
    flash_attn<<<dim3(B_ * H_ * (S_ / 128)), dim3(256), 0, stream>>>(Qb, Kb, Vt, mask, heads);
    gemm_out<<<dim3(64 * 4), dim3(256), 0, stream>>>(heads, Wb, b0, out);
}

// Round 7
// 194.487 us; speedup vs baseline: 1.7352x; 1.7352x over previous
//
#include <hip/hip_runtime.h>

#define B_  4
#define D_  512
#define H_  8
#define DV_ 64
#define S_  2048
#define LOG2E 1.442695041f

typedef __bf16 bf16;
typedef bf16  bf16x8 __attribute__((ext_vector_type(8)));
typedef bf16  bf16x4 __attribute__((ext_vector_type(4)));
typedef float f32x4  __attribute__((ext_vector_type(4)));

#define MFMA(a, b, c) __builtin_amdgcn_mfma_f32_16x16x32_bf16((a), (b), (c), 0, 0, 0)

// async global->LDS, 16B per lane; LDS dest is wave-uniform base + lane*16
#define GLOAD_LDS(g, l)                                                     \
    __builtin_amdgcn_global_load_lds(                                       \
        (const __attribute__((address_space(1))) void*)(g),                 \
        (__attribute__((address_space(3))) void*)(l), 16, 0, 0)

// s_waitcnt with vmcnt(n), lgkm/exp unconstrained (gfx9 encoding)
#define WAIT_VMCNT(n)                                                       \
    __builtin_amdgcn_s_waitcnt(((n) & 15) | (((n) >> 4) << 14) | (7 << 4) | (15 << 8))

// ---------------------------------------------------------------------------
// Kernel 1: prep = transpose x (B,D,S fp32 -> B,S,D bf16)  +  pack weights
// r7: transpose STORE vectorized to bf16x4 (was scalar 2B/lane).
// ---------------------------------------------------------------------------
__global__ __launch_bounds__(256) void prep(
    const float* __restrict__ x, const float* __restrict__ Wq,
    const float* __restrict__ Wk, const float* __restrict__ Wv,
    const float* __restrict__ W0, bf16* __restrict__ xb, bf16* __restrict__ Wb) {
    const int bid = blockIdx.x;
    if (bid < 4096) {                            // transpose part
        __shared__ float tile[32][33];
        const int sblk = bid % 64;               // S/32
        const int dblk = (bid / 64) % 16;        // D/32
        const int b    = bid / 1024;
        const int d0 = dblk * 32, s0 = sblk * 32;
        const int tx = threadIdx.x & 31;
        const int ty = threadIdx.x >> 5;         // 0..7
        const float* xp = x + (size_t)b * D_ * S_;
#pragma unroll
        for (int i = 0; i < 32; i += 8)
            tile[ty + i][tx] = xp[(size_t)(d0 + ty + i) * S_ + s0 + tx];
        __syncthreads();
        // vectorized store: thread -> (s = tid>>3, 4-wide d-chunk = (tid&7)*4)
        bf16* xbp = xb + ((size_t)b * S_ + s0) * D_ + d0;
        const int srow = threadIdx.x >> 3;       // 0..31 (local s)
        const int d4   = (threadIdx.x & 7) * 4;  // 0..28 (local d)
        bf16x4 hv;
#pragma unroll
        for (int j = 0; j < 4; ++j) hv[j] = (bf16)tile[d4 + j][srow];
        *(bf16x4*)&xbp[(size_t)srow * D_ + d4] = hv;
    } else {                                     // weight-pack part: 256 blocks
        const int f0 = ((bid - 4096) * 256 + threadIdx.x) * 16;  // 0..1048560
        const int src = f0 >> 18;                // 262144 elems per matrix
        const int off = f0 & 262143;
        const float* W = (src == 0) ? Wq : (src == 1) ? Wk : (src == 2) ? Wv : W0;
        float4 v0 = *(const float4*)&W[off];
        float4 v1 = *(const float4*)&W[off + 4];
        float4 v2 = *(const float4*)&W[off + 8];
        float4 v3 = *(const float4*)&W[off + 12];
        bf16x8 h0 = {(bf16)v0.x, (bf16)v0.y, (bf16)v0.z, (bf16)v0.w,
                     (bf16)v1.x, (bf16)v1.y, (bf16)v1.z, (bf16)v1.w};
        bf16x8 h1 = {(bf16)v2.x, (bf16)v2.y, (bf16)v2.z, (bf16)v2.w,
                     (bf16)v3.x, (bf16)v3.y, (bf16)v3.z, (bf16)v3.w};
        *(bf16x8*)&Wb[f0]     = h0;
        *(bf16x8*)&Wb[f0 + 8] = h1;
    }
}

// ---------------------------------------------------------------------------
// Kernel 2: fused QKV GEMM, m97-style core (r1-verified). V stored transposed
// + key-swizzled (sigma) for flash's LDS-staged PV fragments. T1 XCD swizzle.
// ---------------------------------------------------------------------------
__global__ __launch_bounds__(256) void gemm_qkv(
    const bf16* __restrict__ A, const bf16* __restrict__ Wb,
    const float* __restrict__ bq, const float* __restrict__ bk,
    const float* __restrict__ bv,
    bf16* __restrict__ Q, bf16* __restrict__ K, bf16* __restrict__ Vt) {
    __shared__ union {
        struct { bf16 A[8192]; bf16 B[8192]; } s;
        bf16 T[128][132];                        // epilogue transpose (33792 B)
    } sm;

    const int tid = threadIdx.x;
    const int w = tid >> 6, lane = tid & 63;
    const int m16 = lane & 15, quad = lane >> 4;
    const int wr = w & 1, wc = w >> 1;

    const int bid  = (blockIdx.x & 7) * 96 + (blockIdx.x >> 3);  // T1 swizzle
    const int nblk = bid % 12;                   // N = 1536 / 128
    const int mblk = bid / 12;                   // M = 8192 / 128
    const int m0 = mblk * 128, n0 = nblk * 128;

    f32x4 acc[4][4];
#pragma unroll
    for (int i = 0; i < 4; ++i)
#pragma unroll
        for (int j = 0; j < 4; ++j) acc[i][j] = (f32x4){0.f, 0.f, 0.f, 0.f};

    for (int k0 = 0; k0 < D_; k0 += 64) {
        __syncthreads();
#pragma unroll
        for (int i = 0; i < 4; ++i) {            // wave w stages chunks w*4..w*4+3
            const int c  = w * 4 + i;
            const int mt = c >> 1, kk = c & 1;
            const int row = mt * 16 + m16;
            const int col = k0 + kk * 32 + quad * 8;
            GLOAD_LDS(&A[(size_t)(m0 + row) * D_ + col],  &sm.s.A[(c * 64 + lane) * 8]);
            GLOAD_LDS(&Wb[(size_t)(n0 + row) * D_ + col], &sm.s.B[(c * 64 + lane) * 8]);
        }
        __syncthreads();
#pragma unroll
        for (int kk = 0; kk < 2; ++kk) {
            bf16x8 af[4], bfv[4];
#pragma unroll
            for (int t = 0; t < 4; ++t) {
                af[t]  = *(const bf16x8*)&sm.s.A[(((wr * 4 + t) * 2 + kk) * 64 + lane) * 8];
                bfv[t] = *(const bf16x8*)&sm.s.B[(((wc * 4 + t) * 2 + kk) * 64 + lane) * 8];
            }
#pragma unroll
            for (int mt = 0; mt < 4; ++mt)
#pragma unroll
                for (int nt = 0; nt < 4; ++nt)
                    acc[mt][nt] = MFMA(af[mt], bfv[nt], acc[mt][nt]);
        }
    }

    const int proj = n0 >> 9;                    // 128-tiles never straddle
    const float* bias = (proj == 0) ? bq : (proj == 1) ? bk : bv;

    if (proj == 2) {                             // V: direct sigma-swizzled store
#pragma unroll
        for (int mt = 0; mt < 4; ++mt)
#pragma unroll
            for (int nt = 0; nt < 4; ++nt) {
                const int nr = (n0 + wc * 64 + nt * 16 + m16) & 511;
                const int h = nr >> 6, e = nr & 63;
                const float bia = bias[nr];
                const int srow = m0 + wr * 64 + mt * 16 + quad * 4;
                const int b = srow >> 11, s = srow & 2047;
                const int s2 = (s & ~31) | (quad * 8 + (mt & 1) * 4);  // sigma
                bf16x4 hv;
#pragma unroll
                for (int r = 0; r < 4; ++r) hv[r] = (bf16)(acc[mt][nt][r] + bia);
                *(bf16x4*)&Vt[(((size_t)b * H_ + h) * DV_ + e) * S_ + s2] = hv;
            }
    } else {                                     // Q/K: LDS transpose -> bf16x8
        __syncthreads();
#pragma unroll
        for (int mt = 0; mt < 4; ++mt)
#pragma unroll
            for (int nt = 0; nt < 4; ++nt) {
                const int nloc = wc * 64 + nt * 16 + m16;
                const float bia = bias[(n0 + nloc) & 511];
#pragma unroll
                for (int r = 0; r < 4; ++r)
                    sm.T[wr * 64 + mt * 16 + quad * 4 + r][nloc] =
                        (bf16)(acc[mt][nt][r] + bia);
            }
        __syncthreads();
        const int rloc = tid >> 1, cb = (tid & 1) * 64;
        const int M = m0 + rloc, b = M >> 11, s = M & 2047;
        const int nrb = (n0 + cb) & 511;
        const int h = nrb >> 6;
        bf16* dst = ((proj == 0) ? Q : K) + (((size_t)b * H_ + h) * S_ + s) * DV_;
#pragma unroll
        for (int u = 0; u < 8; ++u)
            *(bf16x8*)&dst[u * 8] = *(const bf16x8*)&sm.T[rloc][cb + u * 8];
    }
}

// ---------------------------------------------------------------------------
// Kernel 3: flash attention — r4 structure VERBATIM (verified 63.6us):
// key-split waves, wave-private dbuf GLOAD_LDS, zero barriers, split K/V
// waits (12/8, tail 4/0), exp2-domain softmax, sigma-V, XOR LDS swizzles.
// r7 delta: T5 s_setprio(1) around the two pure-MFMA clusters only — our
// zero-barrier independent waves are m191's regime (waves at different
// phases), where setprio measured +4-7%; NOT m190's lockstep null case.
// ---------------------------------------------------------------------------
__global__ __launch_bounds__(256, 2) void flash_attn(
    const bf16* __restrict__ Q, const bf16* __restrict__ K, const bf16* __restrict__ Vt,
    const float* __restrict__ mask, bf16* __restrict__ heads) {
    __shared__ union {
        struct {
            bf16 Kl[2][4][2048];                 // [buf][wave][32 keys x 64 d]
            bf16 Vl[2][4][2048];                 // [buf][wave][64 e x 32 keys]
            float Ms[2048];                      // mask * log2(e)
        } s;
        struct { float O[64][65]; float L[64]; } red;
    } sm;

    // XCD-aware swizzle: contiguous 128-block chunk per XCD (K/V L2 locality)
    const int bid  = blockIdx.x;                 // B*H*(S/64) = 1024
    const int bidx = (bid & 7) * 128 + (bid >> 3);
    const int qblk = bidx & 31;
    const int h    = (bidx >> 5) & 7;
    const int b    = bidx >> 8;
    const int q0   = qblk * 64;

    const int tid = threadIdx.x;
    const int w = tid >> 6, lane = tid & 63;
    const int m16 = lane & 15, quad = lane >> 4;

    const bf16* Qp = Q  + ((size_t)b * H_ + h) * S_ * DV_;
    const bf16* Kp = K  + ((size_t)b * H_ + h) * S_ * DV_;
    const bf16* Vp = Vt + ((size_t)b * H_ + h) * DV_ * S_;
    const float* mp = mask + (size_t)b * S_;

    // per-lane staging constants (swizzle algebra, r1-verified)
    const int krow = lane >> 3;                          // 0..7
    const int kcol = ((lane & 7) ^ krow) * 8;            // elem offset in K row
    const int vrow = lane >> 2;                          // 0..15
    const int vcol = ((lane & 3) ^ (vrow & 3)) * 8;      // elem offset in V row

    // stage mask to LDS pre-scaled into the exp2 domain (retires pre-barrier)
#pragma unroll
    for (int p = 0; p < 2; ++p) {
        const float4 mv = *(const float4*)&mp[(p * 256 + tid) * 4];
        f32x4 t = {mv.x * LOG2E, mv.y * LOG2E, mv.z * LOG2E, mv.w * LOG2E};
        *(f32x4*)&sm.s.Ms[(p * 256 + tid) * 4] = t;
    }

    // Q B-frags for 64 q-rows, pre-scaled by 1/sqrt(64) (exact in bf16)
    bf16x8 qf[4][2];
#pragma unroll
    for (int qt = 0; qt < 4; ++qt)
#pragma unroll
        for (int kk = 0; kk < 2; ++kk) {
            bf16x8 v = *(const bf16x8*)&Qp[(size_t)(q0 + qt * 16 + m16) * DV_ +
                                           kk * 32 + quad * 8];
#pragma unroll
            for (int i = 0; i < 8; ++i) v[i] = (bf16)((float)v[i] * 0.125f);
            qf[qt][kk] = v;
        }

    bf16x8 ones;
#pragma unroll
    for (int i = 0; i < 8; ++i) ones[i] = (bf16)1.0f;

    f32x4 o[4][4];                               // O^T[e=16mt+4quad+r][q=16qt+m16]
    f32x4 lacc[4];
#pragma unroll
    for (int mt = 0; mt < 4; ++mt)
#pragma unroll
        for (int qt = 0; qt < 4; ++qt) o[mt][qt] = (f32x4){0.f, 0.f, 0.f, 0.f};
#pragma unroll
    for (int qt = 0; qt < 4; ++qt) lacc[qt] = (f32x4){0.f, 0.f, 0.f, 0.f};

    // ---- prologue: batch 0 (buf 0), K first then V; barrier drains vmcnt ----
    {
        const int tw = w * 32;
#pragma unroll
        for (int p = 0; p < 4; ++p)
            GLOAD_LDS(&Kp[(size_t)(tw + p * 8 + krow) * DV_ + kcol],
                      &sm.s.Kl[0][w][(p * 64 + lane) * 8]);
#pragma unroll
        for (int p = 0; p < 4; ++p)
            GLOAD_LDS(&Vp[(size_t)(p * 16 + vrow) * S_ + tw + vcol],
                      &sm.s.Vl[0][w][(p * 64 + lane) * 8]);
    }
    __syncthreads();                             // mask visible; batch0 done

    for (int i = 0; i < 16; ++i) {
        const int tw = i * 128 + w * 32;         // this wave's 32 keys
        if (i < 15) {                            // issue batch i+1 -> buf (i+1)&1
            const int twn = tw + 128;
            const int nb = (i + 1) & 1;
#pragma unroll
            for (int p = 0; p < 4; ++p)
                GLOAD_LDS(&Kp[(size_t)(twn + p * 8 + krow) * DV_ + kcol],
                          &sm.s.Kl[nb][w][(p * 64 + lane) * 8]);
#pragma unroll
            for (int p = 0; p < 4; ++p)
                GLOAD_LDS(&Vp[(size_t)(p * 16 + vrow) * S_ + twn + vcol],
                          &sm.s.Vl[nb][w][(p * 64 + lane) * 8]);
            WAIT_VMCNT(12);                      // K(i) in LDS (V(i) may lag)
        } else {
            WAIT_VMCNT(4);                       // K(15) in LDS
        }
        __builtin_amdgcn_sched_barrier(0);
        const int buf = i & 1;

        // K A-frags from LDS (swizzle-inverted: retrieves chunk kk*4+quad)
        bf16x8 kf[2][2];
#pragma unroll
        for (int tt = 0; tt < 2; ++tt)
#pragma unroll
            for (int kk = 0; kk < 2; ++kk)
                kf[tt][kk] = *(const bf16x8*)&sm.s.Kl[buf][w][
                    ((tt * 16 + m16) * 8 + ((kk * 4 + quad) ^ (m16 & 7))) * 8];
        const f32x4 m2a = *(const f32x4*)&sm.s.Ms[tw + quad * 4];
        const f32x4 m2b = *(const f32x4*)&sm.s.Ms[tw + 16 + quad * 4];

        // S^T tiles: sc[tt][qt], lane = p[t=16tt+4quad+r][q=16qt+m16]
        f32x4 sc[2][4];
#pragma unroll
        for (int tt = 0; tt < 2; ++tt)
#pragma unroll
            for (int qt = 0; qt < 4; ++qt) sc[tt][qt] = (f32x4){0.f, 0.f, 0.f, 0.f};
        __builtin_amdgcn_s_setprio(1);
#pragma unroll
        for (int kk = 0; kk < 2; ++kk)
#pragma unroll
            for (int tt = 0; tt < 2; ++tt)
#pragma unroll
                for (int qt = 0; qt < 4; ++qt)
                    sc[tt][qt] = MFMA(kf[tt][kk], qf[qt][kk], sc[tt][qt]);
        __builtin_amdgcn_s_setprio(0);

        // mask + exp2, directly into PV B-frags (in-lane, no LDS)
        f32x4 ngA, ngB;
#pragma unroll
        for (int r = 0; r < 4; ++r) {
            ngA[r] = (m2a[r] - LOG2E) * 8e29f;   // 0 for m=1, -1.15e30 for m=0
            ngB[r] = (m2b[r] - LOG2E) * 8e29f;
        }
        bf16x8 pf[4];
#pragma unroll
        for (int qt = 0; qt < 4; ++qt)
#pragma unroll
            for (int r = 0; r < 4; ++r) {
                pf[qt][r]     = (bf16)__builtin_amdgcn_exp2f(
                    __builtin_fmaf(sc[0][qt][r], m2a[r], ngA[r]));
                pf[qt][4 + r] = (bf16)__builtin_amdgcn_exp2f(
                    __builtin_fmaf(sc[1][qt][r], m2b[r], ngB[r]));
            }

        // l accumulation needs no V — overlap with V landing
#pragma unroll
        for (int qt = 0; qt < 4; ++qt) lacc[qt] = MFMA(ones, pf[qt], lacc[qt]);

        if (i < 15) WAIT_VMCNT(8);               // V(i) in LDS
        else        WAIT_VMCNT(0);
        __builtin_amdgcn_sched_barrier(0);

        // V A-frags from LDS (retrieves chunk quad)
        bf16x8 vf[4];
#pragma unroll
        for (int mt = 0; mt < 4; ++mt)
            vf[mt] = *(const bf16x8*)&sm.s.Vl[buf][w][
                ((mt * 16 + m16) * 4 + (quad ^ (m16 & 3))) * 8];

        // PV
        __builtin_amdgcn_s_setprio(1);
#pragma unroll
        for (int mt = 0; mt < 4; ++mt)
#pragma unroll
            for (int qt = 0; qt < 4; ++qt) o[mt][qt] = MFMA(vf[mt], pf[qt], o[mt][qt]);
        __builtin_amdgcn_s_setprio(0);
    }

    // ---- cross-wave reduction (turn-based accumulate into red) ----
    __syncthreads();
#pragma unroll
    for (int ww = 0; ww < 4; ++ww) {
        if (w == ww) {
#pragma unroll
            for (int mt = 0; mt < 4; ++mt)
#pragma unroll
                for (int qt = 0; qt < 4; ++qt)
#pragma unroll
                    for (int r = 0; r < 4; ++r) {
                        float* slot = &sm.red.O[mt * 16 + quad * 4 + r][qt * 16 + m16];
                        *slot = (ww == 0) ? o[mt][qt][r] : (*slot + o[mt][qt][r]);
                    }
            if (quad == 0)
#pragma unroll
                for (int qt = 0; qt < 4; ++qt) {
                    float* ls = &sm.red.L[qt * 16 + m16];
                    *ls = (ww == 0) ? lacc[qt][0] : (*ls + lacc[qt][0]);
                }
        }
        __syncthreads();
    }

    // ---- final store: thread -> (q = tid>>2, 16-wide e-chunk = (tid&3)*16) ----
    const int ql = tid >> 2, ec = (tid & 3) * 16;
    const float l  = sm.red.L[ql];
    const float qm = mp[q0 + ql];
    const float inv = qm / l;
    bf16x8 hv[2];
#pragma unroll
    for (int c = 0; c < 2; ++c)
#pragma unroll
        for (int i = 0; i < 8; ++i)
            hv[c][i] = (bf16)(sm.red.O[ec + c * 8 + i][ql] * inv);
    bf16* dst = &heads[((size_t)b * S_ + q0 + ql) * D_ + h * DV_ + ec];
    *(bf16x8*)(dst)     = hv[0];
    *(bf16x8*)(dst + 8) = hv[1];
}

// ---------------------------------------------------------------------------
// Kernel 4: out projection. r7: 8 waves/block (512 threads), same 128x128
// tile; wave owns 64x32 (wr=w&1, wc=w>>1 in 0..3), acc[4][2]. Rationale:
// 256 blocks = 1 block/CU; at 4 waves that was 1 wave/SIMD (no latency
// hiding between barriers). 8 waves -> 2 waves/SIMD. Staging split:
// waves 0-3 stage the 16 A-chunks, waves 4-7 the 16 B-chunks (same slot
// formulas). T1 XCD swizzle unchanged.
// ---------------------------------------------------------------------------
__global__ __launch_bounds__(512) void gemm_out(
    const bf16* __restrict__ A, const bf16* __restrict__ Wb,
    const float* __restrict__ b0, float* __restrict__ outp) {
    __shared__ bf16 Asl[8192];
    __shared__ bf16 Bsl[8192];

    const int tid = threadIdx.x;
    const int w = tid >> 6, lane = tid & 63;
    const int m16 = lane & 15, quad = lane >> 4;
    const int wr = w & 1, wc = w >> 1;           // wc in 0..3 (32-col strip)

    const int bid  = (blockIdx.x & 7) * 32 + (blockIdx.x >> 3);  // T1 swizzle
    const int nblk = bid & 3;                    // N = 512 / 128
    const int mblk = bid >> 2;                   // M = 8192 / 128
    const int m0 = mblk * 128, n0 = nblk * 128;

    f32x4 acc[4][2];
#pragma unroll
    for (int i = 0; i < 4; ++i)
#pragma unroll
        for (int j = 0; j < 2; ++j) acc[i][j] = (f32x4){0.f, 0.f, 0.f, 0.f};

    for (int k0 = 0; k0 < D_; k0 += 64) {
        __syncthreads();
        {                                        // wave w stages 4 chunks
            const int cb = (w & 3) * 4;
#pragma unroll
            for (int i = 0; i < 4; ++i) {
                const int c  = cb + i;
                const int mt = c >> 1, kk = c & 1;
                const int row = mt * 16 + m16;
                const int col = k0 + kk * 32 + quad * 8;
                if (w < 4)
                    GLOAD_LDS(&A[(size_t)(m0 + row) * D_ + col],
                              &Asl[(c * 64 + lane) * 8]);
                else
                    GLOAD_LDS(&Wb[(size_t)(1536 + n0 + row) * D_ + col],
                              &Bsl[(c * 64 + lane) * 8]);
            }
        }
        __syncthreads();
#pragma unroll
        for (int kk = 0; kk < 2; ++kk) {
            bf16x8 af[4], bfv[2];
#pragma unroll
            for (int t = 0; t < 4; ++t)
                af[t]  = *(const bf16x8*)&Asl[(((wr * 4 + t) * 2 + kk) * 64 + lane) * 8];
#pragma unroll
            for (int nt = 0; nt < 2; ++nt)
                bfv[nt] = *(const bf16x8*)&Bsl[(((wc * 2 + nt) * 2 + kk) * 64 + lane) * 8];
#pragma unroll
            for (int mt = 0; mt < 4; ++mt)
#pragma unroll
                for (int nt = 0; nt < 2; ++nt)
                    acc[mt][nt] = MFMA(af[mt], bfv[nt], acc[mt][nt]);
        }
    }

#pragma unroll
    for (int mt = 0; mt < 4; ++mt)
#pragma unroll
        for (int nt = 0; nt < 2; ++nt) {
            const int n = n0 + wc * 32 + nt * 16 + m16;
            const float bia = b0[n];
            const int srow = m0 + wr * 64 + mt * 16 + quad * 4;
            const int b = srow >> 11, s = srow & 2047;
            float4 vv;
            vv.x = acc[mt][nt][0] + bia;
            vv.y = acc[mt][nt][1] + bia;
            vv.z = acc[mt][nt][2] + bia;
            vv.w = acc[mt][nt][3] + bia;
            *(float4*)&outp[((size_t)b * D_ + n) * S_ + s] = vv;
        }
}

// ---------------------------------------------------------------------------
extern "C" void kernel_launch(void* const* d_in, const int* in_sizes, int n_in,
                              void* d_out, int out_size, void* d_ws, size_t ws_size,
                              hipStream_t stream) {
    const float* x    = (const float*)d_in[0];
    const float* mask = (const float*)d_in[1];
    const float* Wq   = (const float*)d_in[2];
    const float* bq   = (const float*)d_in[3];
    const float* Wk   = (const float*)d_in[4];
    const float* bk   = (const float*)d_in[5];
    const float* Wv   = (const float*)d_in[6];
    const float* bv   = (const float*)d_in[7];
    const float* W0   = (const float*)d_in[8];
    const float* b0   = (const float*)d_in[9];
    float* out = (float*)d_out;

    char* ws = (char*)d_ws;
    const size_t SEG = (size_t)B_ * S_ * D_ * sizeof(bf16);   // 8 MiB
    bf16* xb    = (bf16*)(ws);            // reused as `heads` after gemm_qkv
    bf16* Qb    = (bf16*)(ws + SEG);
    bf16* Kb    = (bf16*)(ws + 2 * SEG);
    bf16* Vt    = (bf16*)(ws + 3 * SEG);
    bf16* Wb    = (bf16*)(ws + 4 * SEG);  // 2048x512 bf16 = 2 MiB
    bf16* heads = xb;

    prep<<<dim3(4096 + 256), dim3(256), 0, stream>>>(x, Wq, Wk, Wv, W0, xb, Wb);
    gemm_qkv<<<dim3(64 * 12), dim3(256), 0, stream>>>(xb, Wb, bq, bk, bv, Qb, Kb, Vt);
    flash_attn<<<dim3(B_ * H_ * (S_ / 64)), dim3(256), 0, stream>>>(Qb, Kb, Vt, mask, heads);
    gemm_out<<<dim3(64 * 4), dim3(512), 0, stream>>>(heads, Wb, b0, out);
}

// Round 9
// 191.758 us; speedup vs baseline: 1.7599x; 1.0142x over previous
//
#include <hip/hip_runtime.h>

#define B_  4
#define D_  512
#define H_  8
#define DV_ 64
#define S_  2048
#define LOG2E 1.442695041f

typedef __bf16 bf16;
typedef bf16  bf16x8 __attribute__((ext_vector_type(8)));
typedef bf16  bf16x4 __attribute__((ext_vector_type(4)));
typedef float f32x4  __attribute__((ext_vector_type(4)));

#define MFMA(a, b, c) __builtin_amdgcn_mfma_f32_16x16x32_bf16((a), (b), (c), 0, 0, 0)

// async global->LDS, 16B per lane; LDS dest is wave-uniform base + lane*16
#define GLOAD_LDS(g, l)                                                     \
    __builtin_amdgcn_global_load_lds(                                       \
        (const __attribute__((address_space(1))) void*)(g),                 \
        (__attribute__((address_space(3))) void*)(l), 16, 0, 0)

// s_waitcnt with vmcnt(n), lgkm/exp unconstrained (gfx9 encoding)
#define WAIT_VMCNT(n)                                                       \
    __builtin_amdgcn_s_waitcnt(((n) & 15) | (((n) >> 4) << 14) | (7 << 4) | (15 << 8))

// ---------------------------------------------------------------------------
// Kernel 1: prep. r8: transpose rebuilt — 64x64 tiles, float4 global loads
// (16B/lane, was 4B), LDS tile[s][d] so stores read contiguous d (2-way max
// bank aliasing both phases = free), bf16x8 stores. 1024 transpose blocks.
// ---------------------------------------------------------------------------
__global__ __launch_bounds__(256) void prep(
    const float* __restrict__ x, const float* __restrict__ Wq,
    const float* __restrict__ Wk, const float* __restrict__ Wv,
    const float* __restrict__ W0, bf16* __restrict__ xb, bf16* __restrict__ Wb) {
    const int bid = blockIdx.x;
    if (bid < 1024) {                            // transpose: B * D/64 * S/64
        __shared__ float tile[64][65];           // [s][d], 16640 B
        const int sblk = bid & 31;
        const int dblk = (bid >> 5) & 7;
        const int b    = bid >> 8;
        const int d0 = dblk * 64, s0 = sblk * 64;
        const int tx = threadIdx.x & 15;         // float4 col (s)
        const int ty = threadIdx.x >> 4;         // 0..15 (d row)
        const float* xp = x + (size_t)b * D_ * S_;
#pragma unroll
        for (int i = 0; i < 64; i += 16) {
            const float4 v = *(const float4*)&xp[(size_t)(d0 + ty + i) * S_ +
                                                 s0 + tx * 4];
            tile[tx * 4 + 0][ty + i] = v.x;
            tile[tx * 4 + 1][ty + i] = v.y;
            tile[tx * 4 + 2][ty + i] = v.z;
            tile[tx * 4 + 3][ty + i] = v.w;
        }
        __syncthreads();
        bf16* xbp = xb + ((size_t)b * S_ + s0) * D_ + d0;
        const int srow0 = threadIdx.x >> 3;      // 0..31
        const int d8    = (threadIdx.x & 7) * 8; // 0..56
#pragma unroll
        for (int i = 0; i < 2; ++i) {
            const int srow = srow0 + i * 32;
            bf16x8 hv;
#pragma unroll
            for (int j = 0; j < 8; ++j) hv[j] = (bf16)tile[srow][d8 + j];
            *(bf16x8*)&xbp[(size_t)srow * D_ + d8] = hv;
        }
    } else {                                     // weight-pack part: 256 blocks
        const int f0 = ((bid - 1024) * 256 + threadIdx.x) * 16;  // 0..1048560
        const int src = f0 >> 18;                // 262144 elems per matrix
        const int off = f0 & 262143;
        const float* W = (src == 0) ? Wq : (src == 1) ? Wk : (src == 2) ? Wv : W0;
        float4 v0 = *(const float4*)&W[off];
        float4 v1 = *(const float4*)&W[off + 4];
        float4 v2 = *(const float4*)&W[off + 8];
        float4 v3 = *(const float4*)&W[off + 12];
        bf16x8 h0 = {(bf16)v0.x, (bf16)v0.y, (bf16)v0.z, (bf16)v0.w,
                     (bf16)v1.x, (bf16)v1.y, (bf16)v1.z, (bf16)v1.w};
        bf16x8 h1 = {(bf16)v2.x, (bf16)v2.y, (bf16)v2.z, (bf16)v2.w,
                     (bf16)v3.x, (bf16)v3.y, (bf16)v3.z, (bf16)v3.w};
        *(bf16x8*)&Wb[f0]     = h0;
        *(bf16x8*)&Wb[f0 + 8] = h1;
    }
}

// ---------------------------------------------------------------------------
// Kernel 2: fused QKV GEMM. r8: 8 waves/block (512 threads), same 128x128
// tile; wave owns 64x32 (wr=w&1, wc=w>>1 in 0..3), acc[4][2] — halves
// per-wave registers and doubles waves/SIMD for barrier-to-barrier latency
// hiding (r7 gemm_out precedent). Staging: waves 0-3 stage the 16 A-chunks,
// waves 4-7 the 16 B-chunks (same slot formulas). V sigma store and Q/K
// transpose epilogues remapped to the 8-wave geometry (each (row,col)
// written exactly once; algebra checked). T1 XCD swizzle unchanged.
// ---------------------------------------------------------------------------
__global__ __launch_bounds__(512) void gemm_qkv(
    const bf16* __restrict__ A, const bf16* __restrict__ Wb,
    const float* __restrict__ bq, const float* __restrict__ bk,
    const float* __restrict__ bv,
    bf16* __restrict__ Q, bf16* __restrict__ K, bf16* __restrict__ Vt) {
    __shared__ union {
        struct { bf16 A[8192]; bf16 B[8192]; } s;
        bf16 T[128][132];                        // epilogue transpose (33792 B)
    } sm;

    const int tid = threadIdx.x;
    const int w = tid >> 6, lane = tid & 63;
    const int m16 = lane & 15, quad = lane >> 4;
    const int wr = w & 1, wc = w >> 1;           // wc in 0..3 (32-col strip)

    const int bid  = (blockIdx.x & 7) * 96 + (blockIdx.x >> 3);  // T1 swizzle
    const int nblk = bid % 12;                   // N = 1536 / 128
    const int mblk = bid / 12;                   // M = 8192 / 128
    const int m0 = mblk * 128, n0 = nblk * 128;

    f32x4 acc[4][2];
#pragma unroll
    for (int i = 0; i < 4; ++i)
#pragma unroll
        for (int j = 0; j < 2; ++j) acc[i][j] = (f32x4){0.f, 0.f, 0.f, 0.f};

    for (int k0 = 0; k0 < D_; k0 += 64) {
        __syncthreads();
        {                                        // wave w stages 4 chunks
            const int cb = (w & 3) * 4;
#pragma unroll
            for (int i = 0; i < 4; ++i) {
                const int c  = cb + i;
                const int mt = c >> 1, kk = c & 1;
                const int row = mt * 16 + m16;
                const int col = k0 + kk * 32 + quad * 8;
                if (w < 4)
                    GLOAD_LDS(&A[(size_t)(m0 + row) * D_ + col],
                              &sm.s.A[(c * 64 + lane) * 8]);
                else
                    GLOAD_LDS(&Wb[(size_t)(n0 + row) * D_ + col],
                              &sm.s.B[(c * 64 + lane) * 8]);
            }
        }
        __syncthreads();
#pragma unroll
        for (int kk = 0; kk < 2; ++kk) {
            bf16x8 af[4], bfv[2];
#pragma unroll
            for (int t = 0; t < 4; ++t)
                af[t]  = *(const bf16x8*)&sm.s.A[(((wr * 4 + t) * 2 + kk) * 64 + lane) * 8];
#pragma unroll
            for (int nt = 0; nt < 2; ++nt)
                bfv[nt] = *(const bf16x8*)&sm.s.B[(((wc * 2 + nt) * 2 + kk) * 64 + lane) * 8];
#pragma unroll
            for (int mt = 0; mt < 4; ++mt)
#pragma unroll
                for (int nt = 0; nt < 2; ++nt)
                    acc[mt][nt] = MFMA(af[mt], bfv[nt], acc[mt][nt]);
        }
    }

    const int proj = n0 >> 9;                    // 128-tiles never straddle
    const float* bias = (proj == 0) ? bq : (proj == 1) ? bk : bv;

    if (proj == 2) {                             // V: direct sigma-swizzled store
#pragma unroll
        for (int mt = 0; mt < 4; ++mt)
#pragma unroll
            for (int nt = 0; nt < 2; ++nt) {
                const int nr = (n0 + wc * 32 + nt * 16 + m16) & 511;
                const int h = nr >> 6, e = nr & 63;
                const float bia = bias[nr];
                const int srow = m0 + wr * 64 + mt * 16 + quad * 4;
                const int b = srow >> 11, s = srow & 2047;
                const int s2 = (s & ~31) | (quad * 8 + (mt & 1) * 4);  // sigma
                bf16x4 hv;
#pragma unroll
                for (int r = 0; r < 4; ++r) hv[r] = (bf16)(acc[mt][nt][r] + bia);
                *(bf16x4*)&Vt[(((size_t)b * H_ + h) * DV_ + e) * S_ + s2] = hv;
            }
    } else {                                     // Q/K: LDS transpose -> bf16x8
        __syncthreads();
#pragma unroll
        for (int mt = 0; mt < 4; ++mt)
#pragma unroll
            for (int nt = 0; nt < 2; ++nt) {
                const int nloc = wc * 32 + nt * 16 + m16;
                const float bia = bias[(n0 + nloc) & 511];
#pragma unroll
                for (int r = 0; r < 4; ++r)
                    sm.T[wr * 64 + mt * 16 + quad * 4 + r][nloc] =
                        (bf16)(acc[mt][nt][r] + bia);
            }
        __syncthreads();
        const int rloc = tid >> 2, cb = (tid & 3) * 32;
        const int M = m0 + rloc, b = M >> 11, s = M & 2047;
        const int nrb = (n0 + cb) & 511;
        const int h = nrb >> 6, eo = nrb & 63;   // 32-chunk offset within head
        bf16* dst = ((proj == 0) ? Q : K) +
                    (((size_t)b * H_ + h) * S_ + s) * DV_ + eo;
#pragma unroll
        for (int u = 0; u < 4; ++u)
            *(bf16x8*)&dst[u * 8] = *(const bf16x8*)&sm.T[rloc][cb + u * 8];
    }
}

// ---------------------------------------------------------------------------
// Kernel 3: flash attention — r4 structure VERBATIM (verified 63.6us):
// key-split waves, wave-private dbuf GLOAD_LDS, zero barriers, split K/V
// waits (12/8, tail 4/0), exp2-domain softmax, sigma-V, XOR LDS swizzles.
// r8: setprio removed (r7 A/B: neutral/noise, per rigor drop unexplained).
// ---------------------------------------------------------------------------
__global__ __launch_bounds__(256, 2) void flash_attn(
    const bf16* __restrict__ Q, const bf16* __restrict__ K, const bf16* __restrict__ Vt,
    const float* __restrict__ mask, bf16* __restrict__ heads) {
    __shared__ union {
        struct {
            bf16 Kl[2][4][2048];                 // [buf][wave][32 keys x 64 d]
            bf16 Vl[2][4][2048];                 // [buf][wave][64 e x 32 keys]
            float Ms[2048];                      // mask * log2(e)
        } s;
        struct { float O[64][65]; float L[64]; } red;
    } sm;

    // XCD-aware swizzle: contiguous 128-block chunk per XCD (K/V L2 locality)
    const int bid  = blockIdx.x;                 // B*H*(S/64) = 1024
    const int bidx = (bid & 7) * 128 + (bid >> 3);
    const int qblk = bidx & 31;
    const int h    = (bidx >> 5) & 7;
    const int b    = bidx >> 8;
    const int q0   = qblk * 64;

    const int tid = threadIdx.x;
    const int w = tid >> 6, lane = tid & 63;
    const int m16 = lane & 15, quad = lane >> 4;

    const bf16* Qp = Q  + ((size_t)b * H_ + h) * S_ * DV_;
    const bf16* Kp = K  + ((size_t)b * H_ + h) * S_ * DV_;
    const bf16* Vp = Vt + ((size_t)b * H_ + h) * DV_ * S_;
    const float* mp = mask + (size_t)b * S_;

    // per-lane staging constants (swizzle algebra, r1-verified)
    const int krow = lane >> 3;                          // 0..7
    const int kcol = ((lane & 7) ^ krow) * 8;            // elem offset in K row
    const int vrow = lane >> 2;                          // 0..15
    const int vcol = ((lane & 3) ^ (vrow & 3)) * 8;      // elem offset in V row

    // stage mask to LDS pre-scaled into the exp2 domain (retires pre-barrier)
#pragma unroll
    for (int p = 0; p < 2; ++p) {
        const float4 mv = *(const float4*)&mp[(p * 256 + tid) * 4];
        f32x4 t = {mv.x * LOG2E, mv.y * LOG2E, mv.z * LOG2E, mv.w * LOG2E};
        *(f32x4*)&sm.s.Ms[(p * 256 + tid) * 4] = t;
    }

    // Q B-frags for 64 q-rows, pre-scaled by 1/sqrt(64) (exact in bf16)
    bf16x8 qf[4][2];
#pragma unroll
    for (int qt = 0; qt < 4; ++qt)
#pragma unroll
        for (int kk = 0; kk < 2; ++kk) {
            bf16x8 v = *(const bf16x8*)&Qp[(size_t)(q0 + qt * 16 + m16) * DV_ +
                                           kk * 32 + quad * 8];
#pragma unroll
            for (int i = 0; i < 8; ++i) v[i] = (bf16)((float)v[i] * 0.125f);
            qf[qt][kk] = v;
        }

    bf16x8 ones;
#pragma unroll
    for (int i = 0; i < 8; ++i) ones[i] = (bf16)1.0f;

    f32x4 o[4][4];                               // O^T[e=16mt+4quad+r][q=16qt+m16]
    f32x4 lacc[4];
#pragma unroll
    for (int mt = 0; mt < 4; ++mt)
#pragma unroll
        for (int qt = 0; qt < 4; ++qt) o[mt][qt] = (f32x4){0.f, 0.f, 0.f, 0.f};
#pragma unroll
    for (int qt = 0; qt < 4; ++qt) lacc[qt] = (f32x4){0.f, 0.f, 0.f, 0.f};

    // ---- prologue: batch 0 (buf 0), K first then V; barrier drains vmcnt ----
    {
        const int tw = w * 32;
#pragma unroll
        for (int p = 0; p < 4; ++p)
            GLOAD_LDS(&Kp[(size_t)(tw + p * 8 + krow) * DV_ + kcol],
                      &sm.s.Kl[0][w][(p * 64 + lane) * 8]);
#pragma unroll
        for (int p = 0; p < 4; ++p)
            GLOAD_LDS(&Vp[(size_t)(p * 16 + vrow) * S_ + tw + vcol],
                      &sm.s.Vl[0][w][(p * 64 + lane) * 8]);
    }
    __syncthreads();                             // mask visible; batch0 done

    for (int i = 0; i < 16; ++i) {
        const int tw = i * 128 + w * 32;         // this wave's 32 keys
        if (i < 15) {                            // issue batch i+1 -> buf (i+1)&1
            const int twn = tw + 128;
            const int nb = (i + 1) & 1;
#pragma unroll
            for (int p = 0; p < 4; ++p)
                GLOAD_LDS(&Kp[(size_t)(twn + p * 8 + krow) * DV_ + kcol],
                          &sm.s.Kl[nb][w][(p * 64 + lane) * 8]);
#pragma unroll
            for (int p = 0; p < 4; ++p)
                GLOAD_LDS(&Vp[(size_t)(p * 16 + vrow) * S_ + twn + vcol],
                          &sm.s.Vl[nb][w][(p * 64 + lane) * 8]);
            WAIT_VMCNT(12);                      // K(i) in LDS (V(i) may lag)
        } else {
            WAIT_VMCNT(4);                       // K(15) in LDS
        }
        __builtin_amdgcn_sched_barrier(0);
        const int buf = i & 1;

        // K A-frags from LDS (swizzle-inverted: retrieves chunk kk*4+quad)
        bf16x8 kf[2][2];
#pragma unroll
        for (int tt = 0; tt < 2; ++tt)
#pragma unroll
            for (int kk = 0; kk < 2; ++kk)
                kf[tt][kk] = *(const bf16x8*)&sm.s.Kl[buf][w][
                    ((tt * 16 + m16) * 8 + ((kk * 4 + quad) ^ (m16 & 7))) * 8];
        const f32x4 m2a = *(const f32x4*)&sm.s.Ms[tw + quad * 4];
        const f32x4 m2b = *(const f32x4*)&sm.s.Ms[tw + 16 + quad * 4];

        // S^T tiles: sc[tt][qt], lane = p[t=16tt+4quad+r][q=16qt+m16]
        f32x4 sc[2][4];
#pragma unroll
        for (int tt = 0; tt < 2; ++tt)
#pragma unroll
            for (int qt = 0; qt < 4; ++qt) sc[tt][qt] = (f32x4){0.f, 0.f, 0.f, 0.f};
#pragma unroll
        for (int kk = 0; kk < 2; ++kk)
#pragma unroll
            for (int tt = 0; tt < 2; ++tt)
#pragma unroll
                for (int qt = 0; qt < 4; ++qt)
                    sc[tt][qt] = MFMA(kf[tt][kk], qf[qt][kk], sc[tt][qt]);

        // mask + exp2, directly into PV B-frags (in-lane, no LDS)
        f32x4 ngA, ngB;
#pragma unroll
        for (int r = 0; r < 4; ++r) {
            ngA[r] = (m2a[r] - LOG2E) * 8e29f;   // 0 for m=1, -1.15e30 for m=0
            ngB[r] = (m2b[r] - LOG2E) * 8e29f;
        }
        bf16x8 pf[4];
#pragma unroll
        for (int qt = 0; qt < 4; ++qt)
#pragma unroll
            for (int r = 0; r < 4; ++r) {
                pf[qt][r]     = (bf16)__builtin_amdgcn_exp2f(
                    __builtin_fmaf(sc[0][qt][r], m2a[r], ngA[r]));
                pf[qt][4 + r] = (bf16)__builtin_amdgcn_exp2f(
                    __builtin_fmaf(sc[1][qt][r], m2b[r], ngB[r]));
            }

        // l accumulation needs no V — overlap with V landing
#pragma unroll
        for (int qt = 0; qt < 4; ++qt) lacc[qt] = MFMA(ones, pf[qt], lacc[qt]);

        if (i < 15) WAIT_VMCNT(8);               // V(i) in LDS
        else        WAIT_VMCNT(0);
        __builtin_amdgcn_sched_barrier(0);

        // V A-frags from LDS (retrieves chunk quad)
        bf16x8 vf[4];
#pragma unroll
        for (int mt = 0; mt < 4; ++mt)
            vf[mt] = *(const bf16x8*)&sm.s.Vl[buf][w][
                ((mt * 16 + m16) * 4 + (quad ^ (m16 & 3))) * 8];

        // PV
#pragma unroll
        for (int mt = 0; mt < 4; ++mt)
#pragma unroll
            for (int qt = 0; qt < 4; ++qt) o[mt][qt] = MFMA(vf[mt], pf[qt], o[mt][qt]);
    }

    // ---- cross-wave reduction (turn-based accumulate into red) ----
    __syncthreads();
#pragma unroll
    for (int ww = 0; ww < 4; ++ww) {
        if (w == ww) {
#pragma unroll
            for (int mt = 0; mt < 4; ++mt)
#pragma unroll
                for (int qt = 0; qt < 4; ++qt)
#pragma unroll
                    for (int r = 0; r < 4; ++r) {
                        float* slot = &sm.red.O[mt * 16 + quad * 4 + r][qt * 16 + m16];
                        *slot = (ww == 0) ? o[mt][qt][r] : (*slot + o[mt][qt][r]);
                    }
            if (quad == 0)
#pragma unroll
                for (int qt = 0; qt < 4; ++qt) {
                    float* ls = &sm.red.L[qt * 16 + m16];
                    *ls = (ww == 0) ? lacc[qt][0] : (*ls + lacc[qt][0]);
                }
        }
        __syncthreads();
    }

    // ---- final store: thread -> (q = tid>>2, 16-wide e-chunk = (tid&3)*16) ----
    const int ql = tid >> 2, ec = (tid & 3) * 16;
    const float l  = sm.red.L[ql];
    const float qm = mp[q0 + ql];
    const float inv = qm / l;
    bf16x8 hv[2];
#pragma unroll
    for (int c = 0; c < 2; ++c)
#pragma unroll
        for (int i = 0; i < 8; ++i)
            hv[c][i] = (bf16)(sm.red.O[ec + c * 8 + i][ql] * inv);
    bf16* dst = &heads[((size_t)b * S_ + q0 + ql) * D_ + h * DV_ + ec];
    *(bf16x8*)(dst)     = hv[0];
    *(bf16x8*)(dst + 8) = hv[1];
}

// ---------------------------------------------------------------------------
// Kernel 4: out projection — r7 8-wave version (verified). T1 XCD swizzle.
// ---------------------------------------------------------------------------
__global__ __launch_bounds__(512) void gemm_out(
    const bf16* __restrict__ A, const bf16* __restrict__ Wb,
    const float* __restrict__ b0, float* __restrict__ outp) {
    __shared__ bf16 Asl[8192];
    __shared__ bf16 Bsl[8192];

    const int tid = threadIdx.x;
    const int w = tid >> 6, lane = tid & 63;
    const int m16 = lane & 15, quad = lane >> 4;
    const int wr = w & 1, wc = w >> 1;           // wc in 0..3 (32-col strip)

    const int bid  = (blockIdx.x & 7) * 32 + (blockIdx.x >> 3);  // T1 swizzle
    const int nblk = bid & 3;                    // N = 512 / 128
    const int mblk = bid >> 2;                   // M = 8192 / 128
    const int m0 = mblk * 128, n0 = nblk * 128;

    f32x4 acc[4][2];
#pragma unroll
    for (int i = 0; i < 4; ++i)
#pragma unroll
        for (int j = 0; j < 2; ++j) acc[i][j] = (f32x4){0.f, 0.f, 0.f, 0.f};

    for (int k0 = 0; k0 < D_; k0 += 64) {
        __syncthreads();
        {                                        // wave w stages 4 chunks
            const int cb = (w & 3) * 4;
#pragma unroll
            for (int i = 0; i < 4; ++i) {
                const int c  = cb + i;
                const int mt = c >> 1, kk = c & 1;
                const int row = mt * 16 + m16;
                const int col = k0 + kk * 32 + quad * 8;
                if (w < 4)
                    GLOAD_LDS(&A[(size_t)(m0 + row) * D_ + col],
                              &Asl[(c * 64 + lane) * 8]);
                else
                    GLOAD_LDS(&Wb[(size_t)(1536 + n0 + row) * D_ + col],
                              &Bsl[(c * 64 + lane) * 8]);
            }
        }
        __syncthreads();
#pragma unroll
        for (int kk = 0; kk < 2; ++kk) {
            bf16x8 af[4], bfv[2];
#pragma unroll
            for (int t = 0; t < 4; ++t)
                af[t]  = *(const bf16x8*)&Asl[(((wr * 4 + t) * 2 + kk) * 64 + lane) * 8];
#pragma unroll
            for (int nt = 0; nt < 2; ++nt)
                bfv[nt] = *(const bf16x8*)&Bsl[(((wc * 2 + nt) * 2 + kk) * 64 + lane) * 8];
#pragma unroll
            for (int mt = 0; mt < 4; ++mt)
#pragma unroll
                for (int nt = 0; nt < 2; ++nt)
                    acc[mt][nt] = MFMA(af[mt], bfv[nt], acc[mt][nt]);
        }
    }

#pragma unroll
    for (int mt = 0; mt < 4; ++mt)
#pragma unroll
        for (int nt = 0; nt < 2; ++nt) {
            const int n = n0 + wc * 32 + nt * 16 + m16;
            const float bia = b0[n];
            const int srow = m0 + wr * 64 + mt * 16 + quad * 4;
            const int b = srow >> 11, s = srow & 2047;
            float4 vv;
            vv.x = acc[mt][nt][0] + bia;
            vv.y = acc[mt][nt][1] + bia;
            vv.z = acc[mt][nt][2] + bia;
            vv.w = acc[mt][nt][3] + bia;
            *(float4*)&outp[((size_t)b * D_ + n) * S_ + s] = vv;
        }
}

// ---------------------------------------------------------------------------
extern "C" void kernel_launch(void* const* d_in, const int* in_sizes, int n_in,
                              void* d_out, int out_size, void* d_ws, size_t ws_size,
                              hipStream_t stream) {
    const float* x    = (const float*)d_in[0];
    const float* mask = (const float*)d_in[1];
    const float* Wq   = (const float*)d_in[2];
    const float* bq   = (const float*)d_in[3];
    const float* Wk   = (const float*)d_in[4];
    const float* bk   = (const float*)d_in[5];
    const float* Wv   = (const float*)d_in[6];
    const float* bv   = (const float*)d_in[7];
    const float* W0   = (const float*)d_in[8];
    const float* b0   = (const float*)d_in[9];
    float* out = (float*)d_out;

    char* ws = (char*)d_ws;
    const size_t SEG = (size_t)B_ * S_ * D_ * sizeof(bf16);   // 8 MiB
    bf16* xb    = (bf16*)(ws);            // reused as `heads` after gemm_qkv
    bf16* Qb    = (bf16*)(ws + SEG);
    bf16* Kb    = (bf16*)(ws + 2 * SEG);
    bf16* Vt    = (bf16*)(ws + 3 * SEG);
    bf16* Wb    = (bf16*)(ws + 4 * SEG);  // 2048x512 bf16 = 2 MiB
    bf16* heads = xb;

    prep<<<dim3(1024 + 256), dim3(256), 0, stream>>>(x, Wq, Wk, Wv, W0, xb, Wb);
    gemm_qkv<<<dim3(64 * 12), dim3(512), 0, stream>>>(xb, Wb, bq, bk, bv, Qb, Kb, Vt);
    flash_attn<<<dim3(B_ * H_ * (S_ / 64)), dim3(256), 0, stream>>>(Qb, Kb, Vt, mask, heads);
    gemm_out<<<dim3(64 * 4), dim3(512), 0, stream>>>(heads, Wb, b0, out);
}

// Round 10
// 190.994 us; speedup vs baseline: 1.7669x; 1.0040x over previous
//
#include <hip/hip_runtime.h>

#define B_  4
#define D_  512
#define H_  8
#define DV_ 64
#define S_  2048
#define LOG2E 1.442695041f

typedef __bf16 bf16;
typedef bf16  bf16x8 __attribute__((ext_vector_type(8)));
typedef bf16  bf16x4 __attribute__((ext_vector_type(4)));
typedef float f32x4  __attribute__((ext_vector_type(4)));

#define MFMA(a, b, c) __builtin_amdgcn_mfma_f32_16x16x32_bf16((a), (b), (c), 0, 0, 0)

// async global->LDS, 16B per lane; LDS dest is wave-uniform base + lane*16
#define GLOAD_LDS(g, l)                                                     \
    __builtin_amdgcn_global_load_lds(                                       \
        (const __attribute__((address_space(1))) void*)(g),                 \
        (__attribute__((address_space(3))) void*)(l), 16, 0, 0)

// s_waitcnt with vmcnt(n), lgkm/exp unconstrained (gfx9 encoding)
#define WAIT_VMCNT(n)                                                       \
    __builtin_amdgcn_s_waitcnt(((n) & 15) | (((n) >> 4) << 14) | (7 << 4) | (15 << 8))

// ---------------------------------------------------------------------------
// Kernel 1: prep (r8/r9-verified): 64x64 transpose tiles, float4 loads,
// bf16x8 stores + weight pack.
// ---------------------------------------------------------------------------
__global__ __launch_bounds__(256) void prep(
    const float* __restrict__ x, const float* __restrict__ Wq,
    const float* __restrict__ Wk, const float* __restrict__ Wv,
    const float* __restrict__ W0, bf16* __restrict__ xb, bf16* __restrict__ Wb) {
    const int bid = blockIdx.x;
    if (bid < 1024) {                            // transpose: B * D/64 * S/64
        __shared__ float tile[64][65];           // [s][d], 16640 B
        const int sblk = bid & 31;
        const int dblk = (bid >> 5) & 7;
        const int b    = bid >> 8;
        const int d0 = dblk * 64, s0 = sblk * 64;
        const int tx = threadIdx.x & 15;         // float4 col (s)
        const int ty = threadIdx.x >> 4;         // 0..15 (d row)
        const float* xp = x + (size_t)b * D_ * S_;
#pragma unroll
        for (int i = 0; i < 64; i += 16) {
            const float4 v = *(const float4*)&xp[(size_t)(d0 + ty + i) * S_ +
                                                 s0 + tx * 4];
            tile[tx * 4 + 0][ty + i] = v.x;
            tile[tx * 4 + 1][ty + i] = v.y;
            tile[tx * 4 + 2][ty + i] = v.z;
            tile[tx * 4 + 3][ty + i] = v.w;
        }
        __syncthreads();
        bf16* xbp = xb + ((size_t)b * S_ + s0) * D_ + d0;
        const int srow0 = threadIdx.x >> 3;      // 0..31
        const int d8    = (threadIdx.x & 7) * 8; // 0..56
#pragma unroll
        for (int i = 0; i < 2; ++i) {
            const int srow = srow0 + i * 32;
            bf16x8 hv;
#pragma unroll
            for (int j = 0; j < 8; ++j) hv[j] = (bf16)tile[srow][d8 + j];
            *(bf16x8*)&xbp[(size_t)srow * D_ + d8] = hv;
        }
    } else {                                     // weight-pack part: 256 blocks
        const int f0 = ((bid - 1024) * 256 + threadIdx.x) * 16;  // 0..1048560
        const int src = f0 >> 18;                // 262144 elems per matrix
        const int off = f0 & 262143;
        const float* W = (src == 0) ? Wq : (src == 1) ? Wk : (src == 2) ? Wv : W0;
        float4 v0 = *(const float4*)&W[off];
        float4 v1 = *(const float4*)&W[off + 4];
        float4 v2 = *(const float4*)&W[off + 8];
        float4 v3 = *(const float4*)&W[off + 12];
        bf16x8 h0 = {(bf16)v0.x, (bf16)v0.y, (bf16)v0.z, (bf16)v0.w,
                     (bf16)v1.x, (bf16)v1.y, (bf16)v1.z, (bf16)v1.w};
        bf16x8 h1 = {(bf16)v2.x, (bf16)v2.y, (bf16)v2.z, (bf16)v2.w,
                     (bf16)v3.x, (bf16)v3.y, (bf16)v3.z, (bf16)v3.w};
        *(bf16x8*)&Wb[f0]     = h0;
        *(bf16x8*)&Wb[f0 + 8] = h1;
    }
}

// ---------------------------------------------------------------------------
// Kernel 2: fused QKV GEMM. r10: T3-minimum DOUBLE-BUFFERED K-loop.
//  THEORY: old schedule {barrier; STAGE(t); barrier(vmcnt drain); compute(t)}
//  exposes the full global->LDS latency (~350cy) every K-step. New schedule
//  {STAGE(buf^1, t+1); compute(buf, t); __syncthreads()} hides tile t+1's
//  load latency under tile t's MFMAs and halves barriers (2->1 per K-step).
//  __syncthreads() emits the vmcnt(0)+lgkmcnt(0) drain (compiler-verified
//  behavior, m97 asm) — exactly the T3-minimum recipe.
//  LDS 32->64 KB: 2 blocks/CU x 8 waves = 16 waves/CU (4/SIMD) — fine.
//  8-wave geometry, epilogues, sigma-V, T1 swizzle: r8/r9-verified verbatim.
// ---------------------------------------------------------------------------
__global__ __launch_bounds__(512) void gemm_qkv(
    const bf16* __restrict__ A, const bf16* __restrict__ Wb,
    const float* __restrict__ bq, const float* __restrict__ bk,
    const float* __restrict__ bv,
    bf16* __restrict__ Q, bf16* __restrict__ K, bf16* __restrict__ Vt) {
    __shared__ union {
        struct { bf16 A[2][8192]; bf16 B[2][8192]; } s;  // 65536 B dbuf
        bf16 T[128][132];                        // epilogue transpose (33792 B)
    } sm;

    const int tid = threadIdx.x;
    const int w = tid >> 6, lane = tid & 63;
    const int m16 = lane & 15, quad = lane >> 4;
    const int wr = w & 1, wc = w >> 1;           // wc in 0..3 (32-col strip)

    const int bid  = (blockIdx.x & 7) * 96 + (blockIdx.x >> 3);  // T1 swizzle
    const int nblk = bid % 12;                   // N = 1536 / 128
    const int mblk = bid / 12;                   // M = 8192 / 128
    const int m0 = mblk * 128, n0 = nblk * 128;

    // wave w stages 4 chunks of A (w<4) or B (w>=4) for one K-step
#define QKV_STAGE(BUF, K0)                                                   \
    {                                                                        \
        const int cb_ = (w & 3) * 4;                                         \
        _Pragma("unroll")                                                    \
        for (int i_ = 0; i_ < 4; ++i_) {                                     \
            const int c_  = cb_ + i_;                                        \
            const int mt_ = c_ >> 1, kk_ = c_ & 1;                           \
            const int row_ = mt_ * 16 + m16;                                 \
            const int col_ = (K0) + kk_ * 32 + quad * 8;                     \
            if (w < 4)                                                       \
                GLOAD_LDS(&A[(size_t)(m0 + row_) * D_ + col_],               \
                          &sm.s.A[BUF][(c_ * 64 + lane) * 8]);               \
            else                                                             \
                GLOAD_LDS(&Wb[(size_t)(n0 + row_) * D_ + col_],              \
                          &sm.s.B[BUF][(c_ * 64 + lane) * 8]);               \
        }                                                                    \
    }

    f32x4 acc[4][2];
#pragma unroll
    for (int i = 0; i < 4; ++i)
#pragma unroll
        for (int j = 0; j < 2; ++j) acc[i][j] = (f32x4){0.f, 0.f, 0.f, 0.f};

    QKV_STAGE(0, 0);
    __syncthreads();                             // tile 0 visible

    for (int t = 0; t < 8; ++t) {
        const int cur = t & 1;
        if (t < 7) QKV_STAGE(cur ^ 1, (t + 1) * 64);
#pragma unroll
        for (int kk = 0; kk < 2; ++kk) {
            bf16x8 af[4], bfv[2];
#pragma unroll
            for (int tt = 0; tt < 4; ++tt)
                af[tt]  = *(const bf16x8*)&sm.s.A[cur][
                    (((wr * 4 + tt) * 2 + kk) * 64 + lane) * 8];
#pragma unroll
            for (int nt = 0; nt < 2; ++nt)
                bfv[nt] = *(const bf16x8*)&sm.s.B[cur][
                    (((wc * 2 + nt) * 2 + kk) * 64 + lane) * 8];
#pragma unroll
            for (int mt = 0; mt < 4; ++mt)
#pragma unroll
                for (int nt = 0; nt < 2; ++nt)
                    acc[mt][nt] = MFMA(af[mt], bfv[nt], acc[mt][nt]);
        }
        __syncthreads();                         // drains stage(t+1); buf flip
    }
#undef QKV_STAGE

    const int proj = n0 >> 9;                    // 128-tiles never straddle
    const float* bias = (proj == 0) ? bq : (proj == 1) ? bk : bv;

    if (proj == 2) {                             // V: direct sigma-swizzled store
#pragma unroll
        for (int mt = 0; mt < 4; ++mt)
#pragma unroll
            for (int nt = 0; nt < 2; ++nt) {
                const int nr = (n0 + wc * 32 + nt * 16 + m16) & 511;
                const int h = nr >> 6, e = nr & 63;
                const float bia = bias[nr];
                const int srow = m0 + wr * 64 + mt * 16 + quad * 4;
                const int b = srow >> 11, s = srow & 2047;
                const int s2 = (s & ~31) | (quad * 8 + (mt & 1) * 4);  // sigma
                bf16x4 hv;
#pragma unroll
                for (int r = 0; r < 4; ++r) hv[r] = (bf16)(acc[mt][nt][r] + bia);
                *(bf16x4*)&Vt[(((size_t)b * H_ + h) * DV_ + e) * S_ + s2] = hv;
            }
    } else {                                     // Q/K: LDS transpose -> bf16x8
        // final loop barrier already synced; sm.T overlay safe
#pragma unroll
        for (int mt = 0; mt < 4; ++mt)
#pragma unroll
            for (int nt = 0; nt < 2; ++nt) {
                const int nloc = wc * 32 + nt * 16 + m16;
                const float bia = bias[(n0 + nloc) & 511];
#pragma unroll
                for (int r = 0; r < 4; ++r)
                    sm.T[wr * 64 + mt * 16 + quad * 4 + r][nloc] =
                        (bf16)(acc[mt][nt][r] + bia);
            }
        __syncthreads();
        const int rloc = tid >> 2, cb = (tid & 3) * 32;
        const int M = m0 + rloc, b = M >> 11, s = M & 2047;
        const int nrb = (n0 + cb) & 511;
        const int h = nrb >> 6, eo = nrb & 63;   // 32-chunk offset within head
        bf16* dst = ((proj == 0) ? Q : K) +
                    (((size_t)b * H_ + h) * S_ + s) * DV_ + eo;
#pragma unroll
        for (int u = 0; u < 4; ++u)
            *(bf16x8*)&dst[u * 8] = *(const bf16x8*)&sm.T[rloc][cb + u * 8];
    }
}

// ---------------------------------------------------------------------------
// Kernel 3: flash attention — r4 structure VERBATIM (verified 63.6-64.2us):
// key-split waves, wave-private dbuf GLOAD_LDS, zero barriers, split K/V
// waits (12/8, tail 4/0), exp2-domain softmax, sigma-V, XOR LDS swizzles.
// ---------------------------------------------------------------------------
__global__ __launch_bounds__(256, 2) void flash_attn(
    const bf16* __restrict__ Q, const bf16* __restrict__ K, const bf16* __restrict__ Vt,
    const float* __restrict__ mask, bf16* __restrict__ heads) {
    __shared__ union {
        struct {
            bf16 Kl[2][4][2048];                 // [buf][wave][32 keys x 64 d]
            bf16 Vl[2][4][2048];                 // [buf][wave][64 e x 32 keys]
            float Ms[2048];                      // mask * log2(e)
        } s;
        struct { float O[64][65]; float L[64]; } red;
    } sm;

    // XCD-aware swizzle: contiguous 128-block chunk per XCD (K/V L2 locality)
    const int bid  = blockIdx.x;                 // B*H*(S/64) = 1024
    const int bidx = (bid & 7) * 128 + (bid >> 3);
    const int qblk = bidx & 31;
    const int h    = (bidx >> 5) & 7;
    const int b    = bidx >> 8;
    const int q0   = qblk * 64;

    const int tid = threadIdx.x;
    const int w = tid >> 6, lane = tid & 63;
    const int m16 = lane & 15, quad = lane >> 4;

    const bf16* Qp = Q  + ((size_t)b * H_ + h) * S_ * DV_;
    const bf16* Kp = K  + ((size_t)b * H_ + h) * S_ * DV_;
    const bf16* Vp = Vt + ((size_t)b * H_ + h) * DV_ * S_;
    const float* mp = mask + (size_t)b * S_;

    // per-lane staging constants (swizzle algebra, r1-verified)
    const int krow = lane >> 3;                          // 0..7
    const int kcol = ((lane & 7) ^ krow) * 8;            // elem offset in K row
    const int vrow = lane >> 2;                          // 0..15
    const int vcol = ((lane & 3) ^ (vrow & 3)) * 8;      // elem offset in V row

    // stage mask to LDS pre-scaled into the exp2 domain (retires pre-barrier)
#pragma unroll
    for (int p = 0; p < 2; ++p) {
        const float4 mv = *(const float4*)&mp[(p * 256 + tid) * 4];
        f32x4 t = {mv.x * LOG2E, mv.y * LOG2E, mv.z * LOG2E, mv.w * LOG2E};
        *(f32x4*)&sm.s.Ms[(p * 256 + tid) * 4] = t;
    }

    // Q B-frags for 64 q-rows, pre-scaled by 1/sqrt(64) (exact in bf16)
    bf16x8 qf[4][2];
#pragma unroll
    for (int qt = 0; qt < 4; ++qt)
#pragma unroll
        for (int kk = 0; kk < 2; ++kk) {
            bf16x8 v = *(const bf16x8*)&Qp[(size_t)(q0 + qt * 16 + m16) * DV_ +
                                           kk * 32 + quad * 8];
#pragma unroll
            for (int i = 0; i < 8; ++i) v[i] = (bf16)((float)v[i] * 0.125f);
            qf[qt][kk] = v;
        }

    bf16x8 ones;
#pragma unroll
    for (int i = 0; i < 8; ++i) ones[i] = (bf16)1.0f;

    f32x4 o[4][4];                               // O^T[e=16mt+4quad+r][q=16qt+m16]
    f32x4 lacc[4];
#pragma unroll
    for (int mt = 0; mt < 4; ++mt)
#pragma unroll
        for (int qt = 0; qt < 4; ++qt) o[mt][qt] = (f32x4){0.f, 0.f, 0.f, 0.f};
#pragma unroll
    for (int qt = 0; qt < 4; ++qt) lacc[qt] = (f32x4){0.f, 0.f, 0.f, 0.f};

    // ---- prologue: batch 0 (buf 0), K first then V; barrier drains vmcnt ----
    {
        const int tw = w * 32;
#pragma unroll
        for (int p = 0; p < 4; ++p)
            GLOAD_LDS(&Kp[(size_t)(tw + p * 8 + krow) * DV_ + kcol],
                      &sm.s.Kl[0][w][(p * 64 + lane) * 8]);
#pragma unroll
        for (int p = 0; p < 4; ++p)
            GLOAD_LDS(&Vp[(size_t)(p * 16 + vrow) * S_ + tw + vcol],
                      &sm.s.Vl[0][w][(p * 64 + lane) * 8]);
    }
    __syncthreads();                             // mask visible; batch0 done

    for (int i = 0; i < 16; ++i) {
        const int tw = i * 128 + w * 32;         // this wave's 32 keys
        if (i < 15) {                            // issue batch i+1 -> buf (i+1)&1
            const int twn = tw + 128;
            const int nb = (i + 1) & 1;
#pragma unroll
            for (int p = 0; p < 4; ++p)
                GLOAD_LDS(&Kp[(size_t)(twn + p * 8 + krow) * DV_ + kcol],
                          &sm.s.Kl[nb][w][(p * 64 + lane) * 8]);
#pragma unroll
            for (int p = 0; p < 4; ++p)
                GLOAD_LDS(&Vp[(size_t)(p * 16 + vrow) * S_ + twn + vcol],
                          &sm.s.Vl[nb][w][(p * 64 + lane) * 8]);
            WAIT_VMCNT(12);                      // K(i) in LDS (V(i) may lag)
        } else {
            WAIT_VMCNT(4);                       // K(15) in LDS
        }
        __builtin_amdgcn_sched_barrier(0);
        const int buf = i & 1;

        // K A-frags from LDS (swizzle-inverted: retrieves chunk kk*4+quad)
        bf16x8 kf[2][2];
#pragma unroll
        for (int tt = 0; tt < 2; ++tt)
#pragma unroll
            for (int kk = 0; kk < 2; ++kk)
                kf[tt][kk] = *(const bf16x8*)&sm.s.Kl[buf][w][
                    ((tt * 16 + m16) * 8 + ((kk * 4 + quad) ^ (m16 & 7))) * 8];
        const f32x4 m2a = *(const f32x4*)&sm.s.Ms[tw + quad * 4];
        const f32x4 m2b = *(const f32x4*)&sm.s.Ms[tw + 16 + quad * 4];

        // S^T tiles: sc[tt][qt], lane = p[t=16tt+4quad+r][q=16qt+m16]
        f32x4 sc[2][4];
#pragma unroll
        for (int tt = 0; tt < 2; ++tt)
#pragma unroll
            for (int qt = 0; qt < 4; ++qt) sc[tt][qt] = (f32x4){0.f, 0.f, 0.f, 0.f};
#pragma unroll
        for (int kk = 0; kk < 2; ++kk)
#pragma unroll
            for (int tt = 0; tt < 2; ++tt)
#pragma unroll
                for (int qt = 0; qt < 4; ++qt)
                    sc[tt][qt] = MFMA(kf[tt][kk], qf[qt][kk], sc[tt][qt]);

        // mask + exp2, directly into PV B-frags (in-lane, no LDS)
        f32x4 ngA, ngB;
#pragma unroll
        for (int r = 0; r < 4; ++r) {
            ngA[r] = (m2a[r] - LOG2E) * 8e29f;   // 0 for m=1, -1.15e30 for m=0
            ngB[r] = (m2b[r] - LOG2E) * 8e29f;
        }
        bf16x8 pf[4];
#pragma unroll
        for (int qt = 0; qt < 4; ++qt)
#pragma unroll
            for (int r = 0; r < 4; ++r) {
                pf[qt][r]     = (bf16)__builtin_amdgcn_exp2f(
                    __builtin_fmaf(sc[0][qt][r], m2a[r], ngA[r]));
                pf[qt][4 + r] = (bf16)__builtin_amdgcn_exp2f(
                    __builtin_fmaf(sc[1][qt][r], m2b[r], ngB[r]));
            }

        // l accumulation needs no V — overlap with V landing
#pragma unroll
        for (int qt = 0; qt < 4; ++qt) lacc[qt] = MFMA(ones, pf[qt], lacc[qt]);

        if (i < 15) WAIT_VMCNT(8);               // V(i) in LDS
        else        WAIT_VMCNT(0);
        __builtin_amdgcn_sched_barrier(0);

        // V A-frags from LDS (retrieves chunk quad)
        bf16x8 vf[4];
#pragma unroll
        for (int mt = 0; mt < 4; ++mt)
            vf[mt] = *(const bf16x8*)&sm.s.Vl[buf][w][
                ((mt * 16 + m16) * 4 + (quad ^ (m16 & 3))) * 8];

        // PV
#pragma unroll
        for (int mt = 0; mt < 4; ++mt)
#pragma unroll
            for (int qt = 0; qt < 4; ++qt) o[mt][qt] = MFMA(vf[mt], pf[qt], o[mt][qt]);
    }

    // ---- cross-wave reduction (turn-based accumulate into red) ----
    __syncthreads();
#pragma unroll
    for (int ww = 0; ww < 4; ++ww) {
        if (w == ww) {
#pragma unroll
            for (int mt = 0; mt < 4; ++mt)
#pragma unroll
                for (int qt = 0; qt < 4; ++qt)
#pragma unroll
                    for (int r = 0; r < 4; ++r) {
                        float* slot = &sm.red.O[mt * 16 + quad * 4 + r][qt * 16 + m16];
                        *slot = (ww == 0) ? o[mt][qt][r] : (*slot + o[mt][qt][r]);
                    }
            if (quad == 0)
#pragma unroll
                for (int qt = 0; qt < 4; ++qt) {
                    float* ls = &sm.red.L[qt * 16 + m16];
                    *ls = (ww == 0) ? lacc[qt][0] : (*ls + lacc[qt][0]);
                }
        }
        __syncthreads();
    }

    // ---- final store: thread -> (q = tid>>2, 16-wide e-chunk = (tid&3)*16) ----
    const int ql = tid >> 2, ec = (tid & 3) * 16;
    const float l  = sm.red.L[ql];
    const float qm = mp[q0 + ql];
    const float inv = qm / l;
    bf16x8 hv[2];
#pragma unroll
    for (int c = 0; c < 2; ++c)
#pragma unroll
        for (int i = 0; i < 8; ++i)
            hv[c][i] = (bf16)(sm.red.O[ec + c * 8 + i][ql] * inv);
    bf16* dst = &heads[((size_t)b * S_ + q0 + ql) * D_ + h * DV_ + ec];
    *(bf16x8*)(dst)     = hv[0];
    *(bf16x8*)(dst + 8) = hv[1];
}

// ---------------------------------------------------------------------------
// Kernel 4: out projection. r10: same T3-minimum dbuf K-loop as gemm_qkv
// (stage t+1 -> compute t -> one barrier). 8-wave geometry from r7.
// ---------------------------------------------------------------------------
__global__ __launch_bounds__(512) void gemm_out(
    const bf16* __restrict__ A, const bf16* __restrict__ Wb,
    const float* __restrict__ b0, float* __restrict__ outp) {
    __shared__ bf16 Asl[2][8192];
    __shared__ bf16 Bsl[2][8192];

    const int tid = threadIdx.x;
    const int w = tid >> 6, lane = tid & 63;
    const int m16 = lane & 15, quad = lane >> 4;
    const int wr = w & 1, wc = w >> 1;           // wc in 0..3 (32-col strip)

    const int bid  = (blockIdx.x & 7) * 32 + (blockIdx.x >> 3);  // T1 swizzle
    const int nblk = bid & 3;                    // N = 512 / 128
    const int mblk = bid >> 2;                   // M = 8192 / 128
    const int m0 = mblk * 128, n0 = nblk * 128;

#define OUT_STAGE(BUF, K0)                                                   \
    {                                                                        \
        const int cb_ = (w & 3) * 4;                                         \
        _Pragma("unroll")                                                    \
        for (int i_ = 0; i_ < 4; ++i_) {                                     \
            const int c_  = cb_ + i_;                                        \
            const int mt_ = c_ >> 1, kk_ = c_ & 1;                           \
            const int row_ = mt_ * 16 + m16;                                 \
            const int col_ = (K0) + kk_ * 32 + quad * 8;                     \
            if (w < 4)                                                       \
                GLOAD_LDS(&A[(size_t)(m0 + row_) * D_ + col_],               \
                          &Asl[BUF][(c_ * 64 + lane) * 8]);                  \
            else                                                             \
                GLOAD_LDS(&Wb[(size_t)(1536 + n0 + row_) * D_ + col_],       \
                          &Bsl[BUF][(c_ * 64 + lane) * 8]);                  \
        }                                                                    \
    }

    f32x4 acc[4][2];
#pragma unroll
    for (int i = 0; i < 4; ++i)
#pragma unroll
        for (int j = 0; j < 2; ++j) acc[i][j] = (f32x4){0.f, 0.f, 0.f, 0.f};

    OUT_STAGE(0, 0);
    __syncthreads();

    for (int t = 0; t < 8; ++t) {
        const int cur = t & 1;
        if (t < 7) OUT_STAGE(cur ^ 1, (t + 1) * 64);
#pragma unroll
        for (int kk = 0; kk < 2; ++kk) {
            bf16x8 af[4], bfv[2];
#pragma unroll
            for (int tt = 0; tt < 4; ++tt)
                af[tt]  = *(const bf16x8*)&Asl[cur][
                    (((wr * 4 + tt) * 2 + kk) * 64 + lane) * 8];
#pragma unroll
            for (int nt = 0; nt < 2; ++nt)
                bfv[nt] = *(const bf16x8*)&Bsl[cur][
                    (((wc * 2 + nt) * 2 + kk) * 64 + lane) * 8];
#pragma unroll
            for (int mt = 0; mt < 4; ++mt)
#pragma unroll
                for (int nt = 0; nt < 2; ++nt)
                    acc[mt][nt] = MFMA(af[mt], bfv[nt], acc[mt][nt]);
        }
        __syncthreads();
    }
#undef OUT_STAGE

#pragma unroll
    for (int mt = 0; mt < 4; ++mt)
#pragma unroll
        for (int nt = 0; nt < 2; ++nt) {
            const int n = n0 + wc * 32 + nt * 16 + m16;
            const float bia = b0[n];
            const int srow = m0 + wr * 64 + mt * 16 + quad * 4;
            const int b = srow >> 11, s = srow & 2047;
            float4 vv;
            vv.x = acc[mt][nt][0] + bia;
            vv.y = acc[mt][nt][1] + bia;
            vv.z = acc[mt][nt][2] + bia;
            vv.w = acc[mt][nt][3] + bia;
            *(float4*)&outp[((size_t)b * D_ + n) * S_ + s] = vv;
        }
}

// ---------------------------------------------------------------------------
extern "C" void kernel_launch(void* const* d_in, const int* in_sizes, int n_in,
                              void* d_out, int out_size, void* d_ws, size_t ws_size,
                              hipStream_t stream) {
    const float* x    = (const float*)d_in[0];
    const float* mask = (const float*)d_in[1];
    const float* Wq   = (const float*)d_in[2];
    const float* bq   = (const float*)d_in[3];
    const float* Wk   = (const float*)d_in[4];
    const float* bk   = (const float*)d_in[5];
    const float* Wv   = (const float*)d_in[6];
    const float* bv   = (const float*)d_in[7];
    const float* W0   = (const float*)d_in[8];
    const float* b0   = (const float*)d_in[9];
    float* out = (float*)d_out;

    char* ws = (char*)d_ws;
    const size_t SEG = (size_t)B_ * S_ * D_ * sizeof(bf16);   // 8 MiB
    bf16* xb    = (bf16*)(ws);            // reused as `heads` after gemm_qkv
    bf16* Qb    = (bf16*)(ws + SEG);
    bf16* Kb    = (bf16*)(ws + 2 * SEG);
    bf16* Vt    = (bf16*)(ws + 3 * SEG);
    bf16* Wb    = (bf16*)(ws + 4 * SEG);  // 2048x512 bf16 = 2 MiB
    bf16* heads = xb;

    prep<<<dim3(1024 + 256), dim3(256), 0, stream>>>(x, Wq, Wk, Wv, W0, xb, Wb);
    gemm_qkv<<<dim3(64 * 12), dim3(512), 0, stream>>>(xb, Wb, bq, bk, bv, Qb, Kb, Vt);
    flash_attn<<<dim3(B_ * H_ * (S_ / 64)), dim3(256), 0, stream>>>(Qb, Kb, Vt, mask, heads);
    gemm_out<<<dim3(64 * 4), dim3(512), 0, stream>>>(heads, Wb, b0, out);
}